// Round 9
// baseline (957.597 us; speedup 1.0000x reference)
//
#include <hip/hip_runtime.h>
#include <math.h>

#define NN 50000
#define DD 256
#define KK 64
#define HH 8
#define OO 64
#define EE 1600000
#define LRELU_ALPHA 0.2f
#define HK 512   // H*K
#define NX 640   // padded GEMM1 output cols (512 + 16 scores + pad)
#define N3 80    // padded GEMM3 output cols (64 + 2 scores + pad)

typedef __attribute__((ext_vector_type(8))) short short8;
typedef __attribute__((ext_vector_type(4))) float floatx4;

// split f into bf16 hi + bf16 lo (truncation; residual ~2^-16 relative)
__device__ inline void bsplit(float f, unsigned short& h, unsigned short& l) {
    unsigned u = __float_as_uint(f);
    h = (unsigned short)(u >> 16);
    float fh = __uint_as_float(u & 0xffff0000u);
    l = (unsigned short)(__float_as_uint(f - fh) >> 16);
}

// ---------------------------------------------------------------- small prep kernels
// heads_W [h][d][k] -> Bp[d][h*64+k]
__global__ void pack_heads_kernel(const float* __restrict__ hw, float* __restrict__ Bp) {
    int t = blockIdx.x * 256 + threadIdx.x;
    if (t >= HH * DD * KK) return;
    int h = t >> 14;
    int r = t & 16383;
    int d = r >> 6;
    int k = r & 63;
    Bp[d * HK + h * KK + k] = hw[t];
}

// bc = layer_b @ Bp   [512]
__global__ void bias_pack_kernel(const float* __restrict__ b, const float* __restrict__ Bp,
                                 float* __restrict__ bc) {
    int c = blockIdx.x * 256 + threadIdx.x;
    if (c >= HK) return;
    float s = 0.f;
    for (int d = 0; d < DD; d++) s += b[d] * Bp[d * HK + c];
    bc[c] = s;
}

// WextT[col][d] bf16 h/l: col<512 = Wc^T; 512+h = Wc[:,h*64:+64]@a_src; 520+h = @a_dst; else 0
__global__ void build_wext_kernel(const float* __restrict__ Wc, const float* __restrict__ heads_a,
                                  unsigned short* __restrict__ Th, unsigned short* __restrict__ Tl) {
    int t = blockIdx.x * 256 + threadIdx.x;   // t over NX*DD
    int col = t >> 8, d = t & 255;
    if (col >= NX) return;
    float v = 0.f;
    if (col < HK) {
        v = Wc[d * HK + col];
    } else if (col < HK + 8) {
        int h = col - HK;
        for (int k = 0; k < 64; k++) v += Wc[d * HK + h * 64 + k] * heads_a[h * 128 + k];
    } else if (col < HK + 16) {
        int h = col - HK - 8;
        for (int k = 0; k < 64; k++) v += Wc[d * HK + h * 64 + k] * heads_a[h * 128 + 64 + k];
    }
    unsigned short hi, lo;
    bsplit(v, hi, lo);
    Th[(size_t)col * DD + d] = hi;
    Tl[(size_t)col * DD + d] = lo;
}

// bias_ext[NX]: <512 = bc; 512+h = bc_h . a_src; 520+h = bc_h . a_dst; else 0
__global__ void bias_ext_kernel(const float* __restrict__ bc, const float* __restrict__ heads_a,
                                float* __restrict__ be) {
    int c = blockIdx.x * 256 + threadIdx.x;
    if (c >= NX) return;
    float v = 0.f;
    if (c < HK) v = bc[c];
    else if (c < HK + 8) {
        int h = c - HK;
        for (int k = 0; k < 64; k++) v += bc[h * 64 + k] * heads_a[h * 128 + k];
    } else if (c < HK + 16) {
        int h = c - HK - 8;
        for (int k = 0; k < 64; k++) v += bc[h * 64 + k] * heads_a[h * 128 + 64 + k];
    }
    be[c] = v;
}

// eextT[col][k] bf16 h/l: col<64 = end_W^T; 64 = end_W@ea_src; 65 = end_W@ea_dst; else 0
__global__ void build_eext_kernel(const float* __restrict__ eW, const float* __restrict__ ea,
                                  unsigned short* __restrict__ Th, unsigned short* __restrict__ Tl) {
    int t = blockIdx.x * 256 + threadIdx.x;   // t over N3*HK
    int col = t >> 9, k = t & 511;
    if (col >= N3) return;
    float v = 0.f;
    if (col < OO) v = eW[(size_t)k * OO + col];
    else if (col == OO) { for (int j = 0; j < OO; j++) v += eW[(size_t)k * OO + j] * ea[j]; }
    else if (col == OO + 1) { for (int j = 0; j < OO; j++) v += eW[(size_t)k * OO + j] * ea[64 + j]; }
    unsigned short hi, lo;
    bsplit(v, hi, lo);
    Th[(size_t)col * HK + k] = hi;
    Tl[(size_t)col * HK + k] = lo;
}

// x fp32 -> xh/xl bf16 (float4 granularity)
__global__ void split_x_kernel(const float* __restrict__ x, unsigned short* __restrict__ xh,
                               unsigned short* __restrict__ xl) {
    int t = blockIdx.x * 256 + threadIdx.x;   // t over NN*64 float4s
    if (t >= NN * 64) return;
    float4 v = ((const float4*)x)[t];
    ushort4 vh, vl;
    bsplit(v.x, vh.x, vl.x);
    bsplit(v.y, vh.y, vl.y);
    bsplit(v.z, vh.z, vl.z);
    bsplit(v.w, vh.w, vl.w);
    ((ushort4*)xh)[t] = vh;
    ((ushort4*)xl)[t] = vl;
}

// ---------------------------------------------------------------- fp32 SGEMM (tiny Wc only)
#define GM 128
#define GN 128
#define GKT 16
__global__ __launch_bounds__(256) void sgemm128_kernel(
    const float* __restrict__ A, const float* __restrict__ B,
    const float* __restrict__ bias, float* __restrict__ C,
    int M, int N, int K)
{
    __shared__ float As[GKT][GM + 4];
    __shared__ float Bs[GKT][GN + 4];
    int tid = threadIdx.x;
    int row0 = blockIdx.y * GM, col0 = blockIdx.x * GN;
    int tx = tid & 15, ty = tid >> 4;
    int ar = tid >> 1;
    int ac0 = (tid & 1) * 8;
    float acc[8][8] = {};
    for (int k0 = 0; k0 < K; k0 += GKT) {
#pragma unroll
        for (int i = 0; i < 2; i++) {
            int gr = row0 + ar;
            int gc = k0 + ac0 + i * 4;
            float4 v = make_float4(0.f, 0.f, 0.f, 0.f);
            if (gr < M) v = *(const float4*)&A[(size_t)gr * K + gc];
            As[ac0 + i * 4 + 0][ar] = v.x;
            As[ac0 + i * 4 + 1][ar] = v.y;
            As[ac0 + i * 4 + 2][ar] = v.z;
            As[ac0 + i * 4 + 3][ar] = v.w;
        }
#pragma unroll
        for (int i = 0; i < 2; i++) {
            int idx = tid + i * 256;
            int br = idx >> 5;
            int bc = (idx & 31) * 4;
            float4 v = make_float4(0.f, 0.f, 0.f, 0.f);
            int gc = col0 + bc;
            if (gc < N) v = *(const float4*)&B[(size_t)(k0 + br) * N + gc];
            *(float4*)&Bs[br][bc] = v;
        }
        __syncthreads();
#pragma unroll
        for (int k = 0; k < GKT; k++) {
            float4 a0 = *(const float4*)&As[k][ty * 4];
            float4 a1 = *(const float4*)&As[k][64 + ty * 4];
            float4 b0 = *(const float4*)&Bs[k][tx * 4];
            float4 b1 = *(const float4*)&Bs[k][64 + tx * 4];
            float av[8] = {a0.x, a0.y, a0.z, a0.w, a1.x, a1.y, a1.z, a1.w};
            float bv[8] = {b0.x, b0.y, b0.z, b0.w, b1.x, b1.y, b1.z, b1.w};
#pragma unroll
            for (int i = 0; i < 8; i++)
#pragma unroll
                for (int j = 0; j < 8; j++) acc[i][j] += av[i] * bv[j];
        }
        __syncthreads();
    }
#pragma unroll
    for (int i = 0; i < 8; i++) {
        int gr = row0 + (i < 4 ? ty * 4 + i : 64 + ty * 4 + i - 4);
        if (gr >= M) continue;
#pragma unroll
        for (int j = 0; j < 8; j++) {
            int gc = col0 + (j < 4 ? tx * 4 + j : 64 + tx * 4 + j - 4);
            if (gc >= N) continue;
            float v = acc[i][j];
            if (bias) v += bias[gc];
            C[(size_t)gr * N + gc] = v;
        }
    }
}

// ---------------------------------------------------------------- GEMM1: split-bf16 MFMA
// C[M=NN][NX] = (xh+xl) @ (Bh+Bl)^T; 128x128 block, 2x2 waves, BK=32 (K=256).
// Epilogue: col<512 -> Hh_t[h][n][64]; 512..519 -> ssrc_t; 520..527 -> sdst_t.
#define LDA 40  // LDS stride in shorts
__global__ __launch_bounds__(256) void mfma_gemm1_kernel(
    const unsigned short* __restrict__ xh, const unsigned short* __restrict__ xl,
    const unsigned short* __restrict__ BhT, const unsigned short* __restrict__ BlT,
    const float* __restrict__ bias_ext,
    float* __restrict__ Hh_t, float* __restrict__ ssrc_t, float* __restrict__ sdst_t)
{
    __shared__ unsigned short AhL[128 * LDA];
    __shared__ unsigned short AlL[128 * LDA];
    __shared__ unsigned short BhL[128 * LDA];
    __shared__ unsigned short BlL[128 * LDA];
    int tid = threadIdx.x, widx = tid >> 6, lane = tid & 63;
    int row0 = blockIdx.y * 128, col0 = blockIdx.x * 128;
    int wrow = (widx >> 1) * 64, wcol = (widx & 1) * 64;
    int lrow = lane & 15, lq = lane >> 4;
    int sr = tid >> 1;            // 0..127
    int sc = (tid & 1) * 16;      // 0 or 16 (shorts)
    floatx4 acc[4][4] = {};
    for (int k0 = 0; k0 < DD; k0 += 32) {
        int gr = row0 + sr;
        if (gr < NN) {
            size_t ab = (size_t)gr * DD + k0 + sc;
            *(uint4*)&AhL[sr * LDA + sc]     = *(const uint4*)&xh[ab];
            *(uint4*)&AhL[sr * LDA + sc + 8] = *(const uint4*)&xh[ab + 8];
            *(uint4*)&AlL[sr * LDA + sc]     = *(const uint4*)&xl[ab];
            *(uint4*)&AlL[sr * LDA + sc + 8] = *(const uint4*)&xl[ab + 8];
        } else {
            uint4 z = {0, 0, 0, 0};
            *(uint4*)&AhL[sr * LDA + sc] = z;     *(uint4*)&AhL[sr * LDA + sc + 8] = z;
            *(uint4*)&AlL[sr * LDA + sc] = z;     *(uint4*)&AlL[sr * LDA + sc + 8] = z;
        }
        size_t bb = (size_t)(col0 + sr) * DD + k0 + sc;   // col0+sr < NX allocated
        *(uint4*)&BhL[sr * LDA + sc]     = *(const uint4*)&BhT[bb];
        *(uint4*)&BhL[sr * LDA + sc + 8] = *(const uint4*)&BhT[bb + 8];
        *(uint4*)&BlL[sr * LDA + sc]     = *(const uint4*)&BlT[bb];
        *(uint4*)&BlL[sr * LDA + sc + 8] = *(const uint4*)&BlT[bb + 8];
        __syncthreads();
        short8 ah[4], al[4], bh[4], bl[4];
#pragma unroll
        for (int mi = 0; mi < 4; mi++) {
            int r = wrow + mi * 16 + lrow;
            ah[mi] = *(const short8*)&AhL[r * LDA + lq * 8];
            al[mi] = *(const short8*)&AlL[r * LDA + lq * 8];
        }
#pragma unroll
        for (int ni = 0; ni < 4; ni++) {
            int c = wcol + ni * 16 + lrow;
            bh[ni] = *(const short8*)&BhL[c * LDA + lq * 8];
            bl[ni] = *(const short8*)&BlL[c * LDA + lq * 8];
        }
#pragma unroll
        for (int mi = 0; mi < 4; mi++)
#pragma unroll
            for (int ni = 0; ni < 4; ni++) {
                acc[mi][ni] = __builtin_amdgcn_mfma_f32_16x16x32_bf16(al[mi], bh[ni], acc[mi][ni], 0, 0, 0);
                acc[mi][ni] = __builtin_amdgcn_mfma_f32_16x16x32_bf16(ah[mi], bl[ni], acc[mi][ni], 0, 0, 0);
                acc[mi][ni] = __builtin_amdgcn_mfma_f32_16x16x32_bf16(ah[mi], bh[ni], acc[mi][ni], 0, 0, 0);
            }
        __syncthreads();
    }
#pragma unroll
    for (int mi = 0; mi < 4; mi++)
#pragma unroll
        for (int ni = 0; ni < 4; ni++)
#pragma unroll
            for (int r = 0; r < 4; r++) {
                int grow = row0 + wrow + mi * 16 + lq * 4 + r;
                int gcol = col0 + wcol + ni * 16 + lrow;
                if (grow < NN && gcol < HK + 16) {
                    float v = acc[mi][ni][r] + bias_ext[gcol];
                    if (gcol < HK)
                        Hh_t[((size_t)(gcol >> 6) * NN + grow) * 64 + (gcol & 63)] = v;
                    else if (gcol < HK + 8)
                        ssrc_t[(size_t)(gcol - HK) * NN + grow] = v;
                    else
                        sdst_t[(size_t)(gcol - HK - 8) * NN + grow] = v;
                }
            }
}

// ---------------------------------------------------------------- GEMM3: split-bf16 MFMA
// C[M=NN][N3=80] = (hch+hcl) @ eext^T; 64-row blocks, 4 waves x 16 rows, K=512.
// Epilogue: col<64 -> h2; 64 -> s2src; 65 -> s2dst.
__global__ __launch_bounds__(256) void mfma_gemm3_kernel(
    const unsigned short* __restrict__ hch, const unsigned short* __restrict__ hcl,
    const unsigned short* __restrict__ BhT, const unsigned short* __restrict__ BlT,
    float* __restrict__ h2, float* __restrict__ s2src, float* __restrict__ s2dst)
{
    __shared__ unsigned short AhL[64 * LDA];
    __shared__ unsigned short AlL[64 * LDA];
    __shared__ unsigned short BhL[N3 * LDA];
    __shared__ unsigned short BlL[N3 * LDA];
    int tid = threadIdx.x, widx = tid >> 6, lane = tid & 63;
    int row0 = blockIdx.x * 64;
    int wrow = widx * 16;
    int lrow = lane & 15, lq = lane >> 4;
    int sr = tid >> 2;            // 0..63
    int sc = (tid & 3) * 8;       // 0,8,16,24
    floatx4 acc[5] = {};
    for (int k0 = 0; k0 < HK; k0 += 32) {
        int gr = row0 + sr;
        if (gr < NN) {
            size_t ab = (size_t)gr * HK + k0 + sc;
            *(uint4*)&AhL[sr * LDA + sc] = *(const uint4*)&hch[ab];
            *(uint4*)&AlL[sr * LDA + sc] = *(const uint4*)&hcl[ab];
        } else {
            uint4 z = {0, 0, 0, 0};
            *(uint4*)&AhL[sr * LDA + sc] = z;
            *(uint4*)&AlL[sr * LDA + sc] = z;
        }
#pragma unroll
        for (int i = 0; i < 2; i++) {
            int idx = tid + i * 256;
            if (idx < N3 * 4) {
                int r = idx >> 2, c8 = (idx & 3) * 8;
                size_t bb = (size_t)r * HK + k0 + c8;
                *(uint4*)&BhL[r * LDA + c8] = *(const uint4*)&BhT[bb];
                *(uint4*)&BlL[r * LDA + c8] = *(const uint4*)&BlT[bb];
            }
        }
        __syncthreads();
        short8 ah, al, bh[5], bl[5];
        int r = wrow + lrow;
        ah = *(const short8*)&AhL[r * LDA + lq * 8];
        al = *(const short8*)&AlL[r * LDA + lq * 8];
#pragma unroll
        for (int ni = 0; ni < 5; ni++) {
            int c = ni * 16 + lrow;
            bh[ni] = *(const short8*)&BhL[c * LDA + lq * 8];
            bl[ni] = *(const short8*)&BlL[c * LDA + lq * 8];
        }
#pragma unroll
        for (int ni = 0; ni < 5; ni++) {
            acc[ni] = __builtin_amdgcn_mfma_f32_16x16x32_bf16(al, bh[ni], acc[ni], 0, 0, 0);
            acc[ni] = __builtin_amdgcn_mfma_f32_16x16x32_bf16(ah, bl[ni], acc[ni], 0, 0, 0);
            acc[ni] = __builtin_amdgcn_mfma_f32_16x16x32_bf16(ah, bh[ni], acc[ni], 0, 0, 0);
        }
        __syncthreads();
    }
#pragma unroll
    for (int ni = 0; ni < 5; ni++)
#pragma unroll
        for (int r = 0; r < 4; r++) {
            int grow = row0 + wrow + lq * 4 + r;
            int gcol = ni * 16 + lrow;
            if (grow < NN) {
                float v = acc[ni][r];
                if (gcol < OO) h2[(size_t)grow * OO + gcol] = v;
                else if (gcol == OO) s2src[grow] = v;
                else if (gcol == OO + 1) s2dst[grow] = v;
            }
        }
}

// ---------------------------------------------------------------- CSR build
__global__ void hist_kernel(const int* __restrict__ dst, int* __restrict__ deg) {
    int t = blockIdx.x * 256 + threadIdx.x;
    if (t < EE) atomicAdd(&deg[dst[t]], 1);
}

// 3-phase multi-block scan
__global__ void scan1_kernel(const int* __restrict__ deg, int* __restrict__ part,
                             int* __restrict__ bsum) {
    __shared__ int ws_[4];
    int i = blockIdx.x * 256 + threadIdx.x;
    int lane = threadIdx.x & 63, wv = threadIdx.x >> 6;
    int v = (i < NN) ? deg[i] : 0;
    int x = v;
#pragma unroll
    for (int d = 1; d < 64; d <<= 1) {
        int t = __shfl_up(x, d, 64);
        if (lane >= d) x += t;
    }
    if (lane == 63) ws_[wv] = x;
    __syncthreads();
    int add = 0;
    for (int k = 0; k < wv; k++) add += ws_[k];
    x += add;
    if (i < NN) part[i] = x;
    if (threadIdx.x == 255) bsum[blockIdx.x] = x;
}

__global__ void scan2_kernel(int* __restrict__ bsum, int nb) {
    __shared__ int ws_[4];
    int tid = threadIdx.x;
    int lane = tid & 63, wv = tid >> 6;
    int v = (tid < nb) ? bsum[tid] : 0;
    int x = v;
#pragma unroll
    for (int d = 1; d < 64; d <<= 1) {
        int t = __shfl_up(x, d, 64);
        if (lane >= d) x += t;
    }
    if (lane == 63) ws_[wv] = x;
    __syncthreads();
    int add = 0;
    for (int k = 0; k < wv; k++) add += ws_[k];
    x += add;
    if (tid < nb) bsum[tid] = x;
}

__global__ void scan3_kernel(const int* __restrict__ deg, const int* __restrict__ part,
                             const int* __restrict__ bsum, int* __restrict__ offs,
                             int* __restrict__ cursor) {
    int i = blockIdx.x * 256 + threadIdx.x;
    if (i >= NN) return;
    int carry = blockIdx.x ? bsum[blockIdx.x - 1] : 0;
    int incl = part[i] + carry;
    offs[i + 1] = incl;
    cursor[i] = incl - deg[i];
    if (i == 0) offs[0] = 0;
}

__global__ void scatter_kernel(const int* __restrict__ src, const int* __restrict__ dst,
                               int* __restrict__ cursor, int* __restrict__ ssorted) {
    int t = blockIdx.x * 256 + threadIdx.x;
    if (t < EE) {
        int d = dst[t];
        int pos = atomicAdd(&cursor[d], 1);
        ssorted[pos] = src[t];
    }
}

// ---------------------------------------------------------------- head aggregation
// one wave per (node, head), head-major grid. No max-subtraction (|e| < ~6 so
// exp is fp32-safe and the softmax ratio is identical). Per-64-edge chunk:
// score phase (lane=edge) -> (s*256, w) to wave LDS (all 64 entries always
// valid; invalid lanes carry w=0) -> BRANCH-FREE batches of 8 LDS reads ->
// 8 dwordx4 loads -> 32 FMAs. Padded steps read row 0 (L1-hot) with w=0.
#define AP 8
__global__ __launch_bounds__(256) void agg_heads_kernel(
    const float* __restrict__ Hh_t, const float* __restrict__ ssrc_t,
    const float* __restrict__ sdst_t, const int* __restrict__ offs,
    const int* __restrict__ ssorted,
    unsigned short* __restrict__ hch, unsigned short* __restrict__ hcl)
{
    __shared__ int2 sSW[4][64];
    int wv = threadIdx.x >> 6, lane = threadIdx.x & 63;
    int w = blockIdx.x * 4 + wv;
    if (w >= NN * HH) return;
    int h = w / NN, n = w - h * NN;
    const char* Hsb = (const char*)(Hh_t + (size_t)h * NN * 64);
    const float* srcs = ssrc_t + (size_t)h * NN;
    int beg = offs[n], deg = offs[n + 1] - beg;
    int g = lane >> 4, q = lane & 15;
    int qoff = q * 16;
    float4 acc = make_float4(0.f, 0.f, 0.f, 0.f);
    float den = 0.f;
    float sd = (deg > 0) ? sdst_t[(size_t)h * NN + n] : 0.f;
    for (int c0 = 0; c0 < deg; c0 += 64) {
        int jj = c0 + lane;
        int s = 0;
        float wgt = 0.f;
        if (jj < deg) {
            s = ssorted[beg + jj];
            float sv = srcs[s] + sd;
            float e = (sv >= 0.f) ? sv : LRELU_ALPHA * sv;
            wgt = __expf(e);
        }
        den += wgt;
        sSW[wv][lane] = make_int2(s << 8, __float_as_int(wgt));  // s*256 = byte offset
        int clen = min(64, deg - c0);
        int nbat = (clen + 31) >> 5;          // 1 or 2 batches of 8 steps (32 edges)
        for (int b = 0; b < nbat; b++) {
            int base = b * AP;
            int soff[AP];
            float wb[AP];
#pragma unroll
            for (int p2 = 0; p2 < AP; p2++) {
                int2 t2 = sSW[wv][(base + p2) * 4 + g];
                soff[p2] = t2.x;
                wb[p2] = __int_as_float(t2.y);
            }
            float4 vb[AP];
#pragma unroll
            for (int p2 = 0; p2 < AP; p2++)
                vb[p2] = *(const float4*)(Hsb + soff[p2] + qoff);
#pragma unroll
            for (int p2 = 0; p2 < AP; p2++) {
                acc.x += wb[p2] * vb[p2].x;
                acc.y += wb[p2] * vb[p2].y;
                acc.z += wb[p2] * vb[p2].z;
                acc.w += wb[p2] * vb[p2].w;
            }
        }
    }
#pragma unroll
    for (int off = 32; off; off >>= 1) den += __shfl_xor(den, off, 64);
#pragma unroll
    for (int off = 16; off < 64; off <<= 1) {
        acc.x += __shfl_xor(acc.x, off, 64);
        acc.y += __shfl_xor(acc.y, off, 64);
        acc.z += __shfl_xor(acc.z, off, 64);
        acc.w += __shfl_xor(acc.w, off, 64);
    }
    if (g == 0) {
        float inv = 1.f / (den + 1e-16f);
        float r0 = acc.x * inv, r1 = acc.y * inv, r2 = acc.z * inv, r3 = acc.w * inv;
        r0 = (r0 > 0.f) ? r0 : (__expf(r0) - 1.f);
        r1 = (r1 > 0.f) ? r1 : (__expf(r1) - 1.f);
        r2 = (r2 > 0.f) ? r2 : (__expf(r2) - 1.f);
        r3 = (r3 > 0.f) ? r3 : (__expf(r3) - 1.f);
        ushort4 vh, vl;
        bsplit(r0, vh.x, vl.x);
        bsplit(r1, vh.y, vl.y);
        bsplit(r2, vh.z, vl.z);
        bsplit(r3, vh.w, vl.w);
        size_t o = (size_t)n * HK + h * 64 + q * 4;
        unsigned long long ph =
            (unsigned long long)vh.x | ((unsigned long long)vh.y << 16) |
            ((unsigned long long)vh.z << 32) | ((unsigned long long)vh.w << 48);
        unsigned long long pl =
            (unsigned long long)vl.x | ((unsigned long long)vl.y << 16) |
            ((unsigned long long)vl.z << 32) | ((unsigned long long)vl.w << 48);
        __builtin_nontemporal_store(ph, (unsigned long long*)&hch[o]);
        __builtin_nontemporal_store(pl, (unsigned long long*)&hcl[o]);
    }
}

// ---------------------------------------------------------------- final layer + softmax
__global__ __launch_bounds__(256) void agg_final_kernel(
    const float* __restrict__ h2, const float* __restrict__ s2src,
    const float* __restrict__ s2dst, const int* __restrict__ offs,
    const int* __restrict__ ssorted, float* __restrict__ out)
{
    __shared__ int2 sSW[4][64];
    int wv = threadIdx.x >> 6, lane = threadIdx.x & 63;
    int n = blockIdx.x * 4 + wv;
    if (n >= NN) return;
    int beg = offs[n], deg = offs[n + 1] - beg;
    int g = lane >> 4, q = lane & 15;
    int qoff = q * 16;
    const char* h2b = (const char*)h2;
    float4 acc = make_float4(0.f, 0.f, 0.f, 0.f);
    float den = 0.f;
    float sd = (deg > 0) ? s2dst[n] : 0.f;
    for (int c0 = 0; c0 < deg; c0 += 64) {
        int jj = c0 + lane;
        int s = 0;
        float wgt = 0.f;
        if (jj < deg) {
            s = ssorted[beg + jj];
            float sv = s2src[s] + sd;
            float e = (sv >= 0.f) ? sv : LRELU_ALPHA * sv;
            wgt = __expf(e);
        }
        den += wgt;
        sSW[wv][lane] = make_int2(s << 8, __float_as_int(wgt));
        int clen = min(64, deg - c0);
        int nbat = (clen + 31) >> 5;
        for (int b = 0; b < nbat; b++) {
            int base = b * AP;
            int soff[AP];
            float wb[AP];
#pragma unroll
            for (int p2 = 0; p2 < AP; p2++) {
                int2 t2 = sSW[wv][(base + p2) * 4 + g];
                soff[p2] = t2.x;
                wb[p2] = __int_as_float(t2.y);
            }
            float4 vb[AP];
#pragma unroll
            for (int p2 = 0; p2 < AP; p2++)
                vb[p2] = *(const float4*)(h2b + soff[p2] + qoff);
#pragma unroll
            for (int p2 = 0; p2 < AP; p2++) {
                acc.x += wb[p2] * vb[p2].x;
                acc.y += wb[p2] * vb[p2].y;
                acc.z += wb[p2] * vb[p2].z;
                acc.w += wb[p2] * vb[p2].w;
            }
        }
    }
#pragma unroll
    for (int off = 32; off; off >>= 1) den += __shfl_xor(den, off, 64);
#pragma unroll
    for (int off = 16; off < 64; off <<= 1) {
        acc.x += __shfl_xor(acc.x, off, 64);
        acc.y += __shfl_xor(acc.y, off, 64);
        acc.z += __shfl_xor(acc.z, off, 64);
        acc.w += __shfl_xor(acc.w, off, 64);
    }
    float inv = 1.f / (den + 1e-16f);
    float r0 = acc.x * inv, r1 = acc.y * inv, r2 = acc.z * inv, r3 = acc.w * inv;
    r0 = (r0 > 0.f) ? r0 : (__expf(r0) - 1.f);
    r1 = (r1 > 0.f) ? r1 : (__expf(r1) - 1.f);
    r2 = (r2 > 0.f) ? r2 : (__expf(r2) - 1.f);
    r3 = (r3 > 0.f) ? r3 : (__expf(r3) - 1.f);
    float mm = fmaxf(fmaxf(r0, r1), fmaxf(r2, r3));
#pragma unroll
    for (int off = 1; off < 16; off <<= 1) mm = fmaxf(mm, __shfl_xor(mm, off, 64));
    float p0 = __expf(r0 - mm), p1 = __expf(r1 - mm);
    float p2 = __expf(r2 - mm), p3 = __expf(r3 - mm);
    float sum = p0 + p1 + p2 + p3;
#pragma unroll
    for (int off = 1; off < 16; off <<= 1) sum += __shfl_xor(sum, off, 64);
    float is = 1.f / sum;
    if (g == 0) {
        float4 res = make_float4(p0 * is, p1 * is, p2 * is, p3 * is);
        *(float4*)&out[(size_t)n * OO + q * 4] = res;
    }
}

// ---------------------------------------------------------------- launch
extern "C" void kernel_launch(void* const* d_in, const int* in_sizes, int n_in,
                              void* d_out, int out_size, void* d_ws, size_t ws_size,
                              hipStream_t stream) {
    const float* x       = (const float*)d_in[0];
    const int*   edges   = (const int*)d_in[1];
    const float* layer_W = (const float*)d_in[2];
    const float* layer_b = (const float*)d_in[3];
    const float* heads_W = (const float*)d_in[4];
    const float* heads_a = (const float*)d_in[5];
    const float* end_W   = (const float*)d_in[6];
    const float* end_a   = (const float*)d_in[7];
    float* out = (float*)d_out;

    const int* src = edges;
    const int* dst = edges + EE;

    char* ws = (char*)d_ws;
    size_t wsp = 0;
    auto alloc = [&](size_t bytes) -> void* {
        void* r = ws + wsp;
        wsp += (bytes + 255) & ~(size_t)255;
        return r;
    };
    // budget: ~230 MB total (round-4/6/8 footprint, known to fit)
    float* Hh_t  = (float*)alloc((size_t)NN * HK * 4);                  // 102.4 MB
    unsigned short* hch = (unsigned short*)alloc((size_t)NN * HK * 2);  // 51.2 MB
    unsigned short* hcl = (unsigned short*)alloc((size_t)NN * HK * 2);  // 51.2 MB
    float* h2    = (float*)alloc((size_t)NN * OO * 4);                  // 12.8 MB
    float* Bp    = (float*)alloc((size_t)DD * HK * 4);
    float* Wc    = (float*)alloc((size_t)DD * HK * 4);
    float* bc    = (float*)alloc((size_t)HK * 4);
    unsigned short* WexthT = (unsigned short*)alloc((size_t)NX * DD * 2);
    unsigned short* WextlT = (unsigned short*)alloc((size_t)NX * DD * 2);
    unsigned short* eexthT = (unsigned short*)alloc((size_t)N3 * HK * 2);
    unsigned short* eextlT = (unsigned short*)alloc((size_t)N3 * HK * 2);
    float* bias_ext = (float*)alloc((size_t)NX * 4);
    float* ssrc_t = (float*)alloc((size_t)HH * NN * 4);
    float* sdst_t = (float*)alloc((size_t)HH * NN * 4);
    float* s2src = (float*)alloc((size_t)NN * 4);
    float* s2dst = (float*)alloc((size_t)NN * 4);
    int* deg     = (int*)alloc((size_t)NN * 4);
    int* offs    = (int*)alloc((size_t)(NN + 1) * 4);
    int* cursor  = (int*)alloc((size_t)NN * 4);
    int* part    = (int*)alloc((size_t)NN * 4);
    int* bsum    = (int*)alloc((size_t)256 * 4);
    int* ssorted = (int*)alloc((size_t)EE * 4);

    // xh/xl alias hch/hcl: x-splits dead before agg_heads writes hch/hcl
    unsigned short* xh = hch;   // needs NN*DD*2 = 25.6 MB < 51.2 MB
    unsigned short* xl = hcl;

    const int NB = (NN + 255) / 256;   // 196 scan blocks

    (void)hipMemsetAsync(deg, 0, (size_t)NN * 4, stream);

    // weight prep
    pack_heads_kernel<<<(HH * DD * KK + 255) / 256, 256, 0, stream>>>(heads_W, Bp);
    bias_pack_kernel<<<2, 256, 0, stream>>>(layer_b, Bp, bc);
    sgemm128_kernel<<<dim3(HK / GN, DD / GM), 256, 0, stream>>>(
        layer_W, Bp, nullptr, Wc, DD, HK, DD);
    build_wext_kernel<<<(NX * DD + 255) / 256, 256, 0, stream>>>(Wc, heads_a, WexthT, WextlT);
    bias_ext_kernel<<<(NX + 255) / 256, 256, 0, stream>>>(bc, heads_a, bias_ext);
    build_eext_kernel<<<(N3 * HK + 255) / 256, 256, 0, stream>>>(end_W, end_a, eexthT, eextlT);
    split_x_kernel<<<(NN * 64 + 255) / 256, 256, 0, stream>>>(x, xh, xl);

    // GEMM1: Hh_t (head-major) + ssrc_t/sdst_t fused score columns
    mfma_gemm1_kernel<<<dim3(NX / 128, (NN + 127) / 128), 256, 0, stream>>>(
        xh, xl, WexthT, WextlT, bias_ext, Hh_t, ssrc_t, sdst_t);

    // CSR build
    hist_kernel<<<(EE + 255) / 256, 256, 0, stream>>>(dst, deg);
    scan1_kernel<<<NB, 256, 0, stream>>>(deg, part, bsum);
    scan2_kernel<<<1, 256, 0, stream>>>(bsum, NB);
    scan3_kernel<<<NB, 256, 0, stream>>>(deg, part, bsum, offs, cursor);
    scatter_kernel<<<(EE + 255) / 256, 256, 0, stream>>>(src, dst, cursor, ssorted);

    // per-head attention aggregation -> split-bf16 hcat (overwrites xh/xl region)
    agg_heads_kernel<<<(NN * HH + 3) / 4, 256, 0, stream>>>(
        Hh_t, ssrc_t, sdst_t, offs, ssorted, hch, hcl);

    // GEMM3: h2 + s2src/s2dst fused score columns
    mfma_gemm3_kernel<<<(NN + 63) / 64, 256, 0, stream>>>(
        hch, hcl, eexthT, eextlT, h2, s2src, s2dst);

    // final aggregation + elu + row softmax
    agg_final_kernel<<<(NN + 3) / 4, 256, 0, stream>>>(h2, s2src, s2dst, offs, ssorted, out);
}

// Round 10
// 943.610 us; speedup vs baseline: 1.0148x; 1.0148x over previous
//
#include <hip/hip_runtime.h>
#include <math.h>

#define NN 50000
#define DD 256
#define KK 64
#define HH 8
#define OO 64
#define EE 1600000
#define LRELU_ALPHA 0.2f
#define HK 512   // H*K
#define NX 640   // padded GEMM1 output cols (512 + 16 scores + pad)
#define N3 80    // padded GEMM3 output cols (64 + 2 scores + pad)

typedef __attribute__((ext_vector_type(8))) short short8;
typedef __attribute__((ext_vector_type(4))) float floatx4;

// split f into bf16 hi + bf16 lo (truncation; residual ~2^-16 relative)
__device__ inline void bsplit(float f, unsigned short& h, unsigned short& l) {
    unsigned u = __float_as_uint(f);
    h = (unsigned short)(u >> 16);
    float fh = __uint_as_float(u & 0xffff0000u);
    l = (unsigned short)(__float_as_uint(f - fh) >> 16);
}

// ---------------------------------------------------------------- small prep kernels
__global__ void pack_heads_kernel(const float* __restrict__ hw, float* __restrict__ Bp) {
    int t = blockIdx.x * 256 + threadIdx.x;
    if (t >= HH * DD * KK) return;
    int h = t >> 14;
    int r = t & 16383;
    int d = r >> 6;
    int k = r & 63;
    Bp[d * HK + h * KK + k] = hw[t];
}

__global__ void bias_pack_kernel(const float* __restrict__ b, const float* __restrict__ Bp,
                                 float* __restrict__ bc) {
    int c = blockIdx.x * 256 + threadIdx.x;
    if (c >= HK) return;
    float s = 0.f;
    for (int d = 0; d < DD; d++) s += b[d] * Bp[d * HK + c];
    bc[c] = s;
}

__global__ void build_wext_kernel(const float* __restrict__ Wc, const float* __restrict__ heads_a,
                                  unsigned short* __restrict__ Th, unsigned short* __restrict__ Tl) {
    int t = blockIdx.x * 256 + threadIdx.x;   // t over NX*DD
    int col = t >> 8, d = t & 255;
    if (col >= NX) return;
    float v = 0.f;
    if (col < HK) {
        v = Wc[d * HK + col];
    } else if (col < HK + 8) {
        int h = col - HK;
        for (int k = 0; k < 64; k++) v += Wc[d * HK + h * 64 + k] * heads_a[h * 128 + k];
    } else if (col < HK + 16) {
        int h = col - HK - 8;
        for (int k = 0; k < 64; k++) v += Wc[d * HK + h * 64 + k] * heads_a[h * 128 + 64 + k];
    }
    unsigned short hi, lo;
    bsplit(v, hi, lo);
    Th[(size_t)col * DD + d] = hi;
    Tl[(size_t)col * DD + d] = lo;
}

__global__ void bias_ext_kernel(const float* __restrict__ bc, const float* __restrict__ heads_a,
                                float* __restrict__ be) {
    int c = blockIdx.x * 256 + threadIdx.x;
    if (c >= NX) return;
    float v = 0.f;
    if (c < HK) v = bc[c];
    else if (c < HK + 8) {
        int h = c - HK;
        for (int k = 0; k < 64; k++) v += bc[h * 64 + k] * heads_a[h * 128 + k];
    } else if (c < HK + 16) {
        int h = c - HK - 8;
        for (int k = 0; k < 64; k++) v += bc[h * 64 + k] * heads_a[h * 128 + 64 + k];
    }
    be[c] = v;
}

__global__ void build_eext_kernel(const float* __restrict__ eW, const float* __restrict__ ea,
                                  unsigned short* __restrict__ Th, unsigned short* __restrict__ Tl) {
    int t = blockIdx.x * 256 + threadIdx.x;   // t over N3*HK
    int col = t >> 9, k = t & 511;
    if (col >= N3) return;
    float v = 0.f;
    if (col < OO) v = eW[(size_t)k * OO + col];
    else if (col == OO) { for (int j = 0; j < OO; j++) v += eW[(size_t)k * OO + j] * ea[j]; }
    else if (col == OO + 1) { for (int j = 0; j < OO; j++) v += eW[(size_t)k * OO + j] * ea[64 + j]; }
    unsigned short hi, lo;
    bsplit(v, hi, lo);
    Th[(size_t)col * HK + k] = hi;
    Tl[(size_t)col * HK + k] = lo;
}

__global__ void split_x_kernel(const float* __restrict__ x, unsigned short* __restrict__ xh,
                               unsigned short* __restrict__ xl) {
    int t = blockIdx.x * 256 + threadIdx.x;   // t over NN*64 float4s
    if (t >= NN * 64) return;
    float4 v = ((const float4*)x)[t];
    ushort4 vh, vl;
    bsplit(v.x, vh.x, vl.x);
    bsplit(v.y, vh.y, vl.y);
    bsplit(v.z, vh.z, vl.z);
    bsplit(v.w, vh.w, vl.w);
    ((ushort4*)xh)[t] = vh;
    ((ushort4*)xl)[t] = vl;
}

// ---------------------------------------------------------------- fp32 SGEMM (tiny Wc only)
#define GM 128
#define GN 128
#define GKT 16
__global__ __launch_bounds__(256) void sgemm128_kernel(
    const float* __restrict__ A, const float* __restrict__ B,
    const float* __restrict__ bias, float* __restrict__ C,
    int M, int N, int K)
{
    __shared__ float As[GKT][GM + 4];
    __shared__ float Bs[GKT][GN + 4];
    int tid = threadIdx.x;
    int row0 = blockIdx.y * GM, col0 = blockIdx.x * GN;
    int tx = tid & 15, ty = tid >> 4;
    int ar = tid >> 1;
    int ac0 = (tid & 1) * 8;
    float acc[8][8] = {};
    for (int k0 = 0; k0 < K; k0 += GKT) {
#pragma unroll
        for (int i = 0; i < 2; i++) {
            int gr = row0 + ar;
            int gc = k0 + ac0 + i * 4;
            float4 v = make_float4(0.f, 0.f, 0.f, 0.f);
            if (gr < M) v = *(const float4*)&A[(size_t)gr * K + gc];
            As[ac0 + i * 4 + 0][ar] = v.x;
            As[ac0 + i * 4 + 1][ar] = v.y;
            As[ac0 + i * 4 + 2][ar] = v.z;
            As[ac0 + i * 4 + 3][ar] = v.w;
        }
#pragma unroll
        for (int i = 0; i < 2; i++) {
            int idx = tid + i * 256;
            int br = idx >> 5;
            int bc = (idx & 31) * 4;
            float4 v = make_float4(0.f, 0.f, 0.f, 0.f);
            int gc = col0 + bc;
            if (gc < N) v = *(const float4*)&B[(size_t)(k0 + br) * N + gc];
            *(float4*)&Bs[br][bc] = v;
        }
        __syncthreads();
#pragma unroll
        for (int k = 0; k < GKT; k++) {
            float4 a0 = *(const float4*)&As[k][ty * 4];
            float4 a1 = *(const float4*)&As[k][64 + ty * 4];
            float4 b0 = *(const float4*)&Bs[k][tx * 4];
            float4 b1 = *(const float4*)&Bs[k][64 + tx * 4];
            float av[8] = {a0.x, a0.y, a0.z, a0.w, a1.x, a1.y, a1.z, a1.w};
            float bv[8] = {b0.x, b0.y, b0.z, b0.w, b1.x, b1.y, b1.z, b1.w};
#pragma unroll
            for (int i = 0; i < 8; i++)
#pragma unroll
                for (int j = 0; j < 8; j++) acc[i][j] += av[i] * bv[j];
        }
        __syncthreads();
    }
#pragma unroll
    for (int i = 0; i < 8; i++) {
        int gr = row0 + (i < 4 ? ty * 4 + i : 64 + ty * 4 + i - 4);
        if (gr >= M) continue;
#pragma unroll
        for (int j = 0; j < 8; j++) {
            int gc = col0 + (j < 4 ? tx * 4 + j : 64 + tx * 4 + j - 4);
            if (gc >= N) continue;
            float v = acc[i][j];
            if (bias) v += bias[gc];
            C[(size_t)gr * N + gc] = v;
        }
    }
}

// ---------------------------------------------------------------- GEMM1: split-bf16 MFMA
// Software-pipelined: prefetch next K-tile into registers during MFMA.
// OOB A-rows load dummy row 0 (outputs masked in epilogue).
#define LDA 40  // LDS stride in shorts
__global__ __launch_bounds__(256) void mfma_gemm1_kernel(
    const unsigned short* __restrict__ xh, const unsigned short* __restrict__ xl,
    const unsigned short* __restrict__ BhT, const unsigned short* __restrict__ BlT,
    const float* __restrict__ bias_ext,
    float* __restrict__ Hh_t, float* __restrict__ ssrc_t, float* __restrict__ sdst_t)
{
    __shared__ unsigned short AhL[128 * LDA];
    __shared__ unsigned short AlL[128 * LDA];
    __shared__ unsigned short BhL[128 * LDA];
    __shared__ unsigned short BlL[128 * LDA];
    int tid = threadIdx.x, widx = tid >> 6, lane = tid & 63;
    int row0 = blockIdx.y * 128, col0 = blockIdx.x * 128;
    int wrow = (widx >> 1) * 64, wcol = (widx & 1) * 64;
    int lrow = lane & 15, lq = lane >> 4;
    int sr = tid >> 1;            // 0..127
    int sc = (tid & 1) * 16;      // 0 or 16 (shorts)
    int gr = row0 + sr;
    size_t abase = (gr < NN) ? (size_t)gr * DD : 0;   // dummy row 0 if OOB (masked later)
    size_t bbase = (size_t)(col0 + sr) * DD;
    floatx4 acc[4][4] = {};
    uint4 pah0, pah1, pal0, pal1, pbh0, pbh1, pbl0, pbl1;
    {
        size_t ab = abase + sc, bb = bbase + sc;
        pah0 = *(const uint4*)&xh[ab];   pah1 = *(const uint4*)&xh[ab + 8];
        pal0 = *(const uint4*)&xl[ab];   pal1 = *(const uint4*)&xl[ab + 8];
        pbh0 = *(const uint4*)&BhT[bb];  pbh1 = *(const uint4*)&BhT[bb + 8];
        pbl0 = *(const uint4*)&BlT[bb];  pbl1 = *(const uint4*)&BlT[bb + 8];
    }
    for (int k0 = 0; k0 < DD; k0 += 32) {
        *(uint4*)&AhL[sr * LDA + sc]     = pah0;
        *(uint4*)&AhL[sr * LDA + sc + 8] = pah1;
        *(uint4*)&AlL[sr * LDA + sc]     = pal0;
        *(uint4*)&AlL[sr * LDA + sc + 8] = pal1;
        *(uint4*)&BhL[sr * LDA + sc]     = pbh0;
        *(uint4*)&BhL[sr * LDA + sc + 8] = pbh1;
        *(uint4*)&BlL[sr * LDA + sc]     = pbl0;
        *(uint4*)&BlL[sr * LDA + sc + 8] = pbl1;
        __syncthreads();
        if (k0 + 32 < DD) {
            size_t ab = abase + k0 + 32 + sc, bb = bbase + k0 + 32 + sc;
            pah0 = *(const uint4*)&xh[ab];   pah1 = *(const uint4*)&xh[ab + 8];
            pal0 = *(const uint4*)&xl[ab];   pal1 = *(const uint4*)&xl[ab + 8];
            pbh0 = *(const uint4*)&BhT[bb];  pbh1 = *(const uint4*)&BhT[bb + 8];
            pbl0 = *(const uint4*)&BlT[bb];  pbl1 = *(const uint4*)&BlT[bb + 8];
        }
        short8 ah[4], al[4], bh[4], bl[4];
#pragma unroll
        for (int mi = 0; mi < 4; mi++) {
            int r = wrow + mi * 16 + lrow;
            ah[mi] = *(const short8*)&AhL[r * LDA + lq * 8];
            al[mi] = *(const short8*)&AlL[r * LDA + lq * 8];
        }
#pragma unroll
        for (int ni = 0; ni < 4; ni++) {
            int c = wcol + ni * 16 + lrow;
            bh[ni] = *(const short8*)&BhL[c * LDA + lq * 8];
            bl[ni] = *(const short8*)&BlL[c * LDA + lq * 8];
        }
#pragma unroll
        for (int mi = 0; mi < 4; mi++)
#pragma unroll
            for (int ni = 0; ni < 4; ni++) {
                acc[mi][ni] = __builtin_amdgcn_mfma_f32_16x16x32_bf16(al[mi], bh[ni], acc[mi][ni], 0, 0, 0);
                acc[mi][ni] = __builtin_amdgcn_mfma_f32_16x16x32_bf16(ah[mi], bl[ni], acc[mi][ni], 0, 0, 0);
                acc[mi][ni] = __builtin_amdgcn_mfma_f32_16x16x32_bf16(ah[mi], bh[ni], acc[mi][ni], 0, 0, 0);
            }
        __syncthreads();
    }
#pragma unroll
    for (int mi = 0; mi < 4; mi++)
#pragma unroll
        for (int ni = 0; ni < 4; ni++)
#pragma unroll
            for (int r = 0; r < 4; r++) {
                int grow = row0 + wrow + mi * 16 + lq * 4 + r;
                int gcol = col0 + wcol + ni * 16 + lrow;
                if (grow < NN && gcol < HK + 16) {
                    float v = acc[mi][ni][r] + bias_ext[gcol];
                    if (gcol < HK)
                        Hh_t[((size_t)(gcol >> 6) * NN + grow) * 64 + (gcol & 63)] = v;
                    else if (gcol < HK + 8)
                        ssrc_t[(size_t)(gcol - HK) * NN + grow] = v;
                    else
                        sdst_t[(size_t)(gcol - HK - 8) * NN + grow] = v;
                }
            }
}

// ---------------------------------------------------------------- GEMM3: split-bf16 MFMA
// Software-pipelined like GEMM1. 64-row blocks, 4 waves x 16 rows, K=512.
__global__ __launch_bounds__(256) void mfma_gemm3_kernel(
    const unsigned short* __restrict__ hch, const unsigned short* __restrict__ hcl,
    const unsigned short* __restrict__ BhT, const unsigned short* __restrict__ BlT,
    float* __restrict__ h2, float* __restrict__ s2src, float* __restrict__ s2dst)
{
    __shared__ unsigned short AhL[64 * LDA];
    __shared__ unsigned short AlL[64 * LDA];
    __shared__ unsigned short BhL[N3 * LDA];
    __shared__ unsigned short BlL[N3 * LDA];
    int tid = threadIdx.x, widx = tid >> 6, lane = tid & 63;
    int row0 = blockIdx.x * 64;
    int wrow = widx * 16;
    int lrow = lane & 15, lq = lane >> 4;
    int sr = tid >> 2;            // 0..63
    int sc = (tid & 3) * 8;       // 0,8,16,24
    int gr = row0 + sr;
    size_t abase = (gr < NN) ? (size_t)gr * HK : 0;
    int bidx0 = tid;              // always < 320
    int br0 = bidx0 >> 2, bc0 = (bidx0 & 3) * 8;
    int bidx1 = tid + 256;
    bool b1ok = (bidx1 < N3 * 4);
    int br1 = bidx1 >> 2, bc1 = (bidx1 & 3) * 8;
    floatx4 acc[5] = {};
    uint4 pa0, pa1, pb0h, pb0l, pb1h, pb1l;
    {
        pa0 = *(const uint4*)&hch[abase + sc];
        pa1 = *(const uint4*)&hcl[abase + sc];
        pb0h = *(const uint4*)&BhT[(size_t)br0 * HK + bc0];
        pb0l = *(const uint4*)&BlT[(size_t)br0 * HK + bc0];
        if (b1ok) {
            pb1h = *(const uint4*)&BhT[(size_t)br1 * HK + bc1];
            pb1l = *(const uint4*)&BlT[(size_t)br1 * HK + bc1];
        }
    }
    for (int k0 = 0; k0 < HK; k0 += 32) {
        *(uint4*)&AhL[sr * LDA + sc] = pa0;
        *(uint4*)&AlL[sr * LDA + sc] = pa1;
        *(uint4*)&BhL[br0 * LDA + bc0] = pb0h;
        *(uint4*)&BlL[br0 * LDA + bc0] = pb0l;
        if (b1ok) {
            *(uint4*)&BhL[br1 * LDA + bc1] = pb1h;
            *(uint4*)&BlL[br1 * LDA + bc1] = pb1l;
        }
        __syncthreads();
        if (k0 + 32 < HK) {
            size_t ab = abase + k0 + 32 + sc;
            pa0 = *(const uint4*)&hch[ab];
            pa1 = *(const uint4*)&hcl[ab];
            pb0h = *(const uint4*)&BhT[(size_t)br0 * HK + k0 + 32 + bc0];
            pb0l = *(const uint4*)&BlT[(size_t)br0 * HK + k0 + 32 + bc0];
            if (b1ok) {
                pb1h = *(const uint4*)&BhT[(size_t)br1 * HK + k0 + 32 + bc1];
                pb1l = *(const uint4*)&BlT[(size_t)br1 * HK + k0 + 32 + bc1];
            }
        }
        short8 ah, al, bh[5], bl[5];
        int r = wrow + lrow;
        ah = *(const short8*)&AhL[r * LDA + lq * 8];
        al = *(const short8*)&AlL[r * LDA + lq * 8];
#pragma unroll
        for (int ni = 0; ni < 5; ni++) {
            int c = ni * 16 + lrow;
            bh[ni] = *(const short8*)&BhL[c * LDA + lq * 8];
            bl[ni] = *(const short8*)&BlL[c * LDA + lq * 8];
        }
#pragma unroll
        for (int ni = 0; ni < 5; ni++) {
            acc[ni] = __builtin_amdgcn_mfma_f32_16x16x32_bf16(al, bh[ni], acc[ni], 0, 0, 0);
            acc[ni] = __builtin_amdgcn_mfma_f32_16x16x32_bf16(ah, bl[ni], acc[ni], 0, 0, 0);
            acc[ni] = __builtin_amdgcn_mfma_f32_16x16x32_bf16(ah, bh[ni], acc[ni], 0, 0, 0);
        }
        __syncthreads();
    }
#pragma unroll
    for (int ni = 0; ni < 5; ni++)
#pragma unroll
        for (int r = 0; r < 4; r++) {
            int grow = row0 + wrow + lq * 4 + r;
            int gcol = ni * 16 + lrow;
            if (grow < NN) {
                float v = acc[ni][r];
                if (gcol < OO) h2[(size_t)grow * OO + gcol] = v;
                else if (gcol == OO) s2src[grow] = v;
                else if (gcol == OO + 1) s2dst[grow] = v;
            }
        }
}

// ---------------------------------------------------------------- CSR build
__global__ void hist_kernel(const int* __restrict__ dst, int* __restrict__ deg) {
    int t = blockIdx.x * 256 + threadIdx.x;
    if (t < EE) atomicAdd(&deg[dst[t]], 1);
}

__global__ void scan1_kernel(const int* __restrict__ deg, int* __restrict__ part,
                             int* __restrict__ bsum) {
    __shared__ int ws_[4];
    int i = blockIdx.x * 256 + threadIdx.x;
    int lane = threadIdx.x & 63, wv = threadIdx.x >> 6;
    int v = (i < NN) ? deg[i] : 0;
    int x = v;
#pragma unroll
    for (int d = 1; d < 64; d <<= 1) {
        int t = __shfl_up(x, d, 64);
        if (lane >= d) x += t;
    }
    if (lane == 63) ws_[wv] = x;
    __syncthreads();
    int add = 0;
    for (int k = 0; k < wv; k++) add += ws_[k];
    x += add;
    if (i < NN) part[i] = x;
    if (threadIdx.x == 255) bsum[blockIdx.x] = x;
}

__global__ void scan2_kernel(int* __restrict__ bsum, int nb) {
    __shared__ int ws_[4];
    int tid = threadIdx.x;
    int lane = tid & 63, wv = tid >> 6;
    int v = (tid < nb) ? bsum[tid] : 0;
    int x = v;
#pragma unroll
    for (int d = 1; d < 64; d <<= 1) {
        int t = __shfl_up(x, d, 64);
        if (lane >= d) x += t;
    }
    if (lane == 63) ws_[wv] = x;
    __syncthreads();
    int add = 0;
    for (int k = 0; k < wv; k++) add += ws_[k];
    x += add;
    if (tid < nb) bsum[tid] = x;
}

__global__ void scan3_kernel(const int* __restrict__ deg, const int* __restrict__ part,
                             const int* __restrict__ bsum, int* __restrict__ offs,
                             int* __restrict__ cursor) {
    int i = blockIdx.x * 256 + threadIdx.x;
    if (i >= NN) return;
    int carry = blockIdx.x ? bsum[blockIdx.x - 1] : 0;
    int incl = part[i] + carry;
    offs[i + 1] = incl;
    cursor[i] = incl - deg[i];
    if (i == 0) offs[0] = 0;
}

__global__ void scatter_kernel(const int* __restrict__ src, const int* __restrict__ dst,
                               int* __restrict__ cursor, int* __restrict__ ssorted) {
    int t = blockIdx.x * 256 + threadIdx.x;
    if (t < EE) {
        int d = dst[t];
        int pos = atomicAdd(&cursor[d], 1);
        ssorted[pos] = src[t];
    }
}

// ---------------------------------------------------------------- head aggregation
// one wave per (node, head), head-major grid. No max-subtraction (|e| < ~6).
// Per-64-edge chunk: scores (lane=edge) -> (s*256, w) in wave LDS -> branch-free
// AP=4 batches (4 LDS reads -> 4 dwordx4 loads -> 16 FMAs). ~24 live VGPRs per
// batch keeps occupancy high (r9's AP=8 hit VGPR=60, occupancy 41% - regressed).
#define AP 4
__global__ __launch_bounds__(256) void agg_heads_kernel(
    const float* __restrict__ Hh_t, const float* __restrict__ ssrc_t,
    const float* __restrict__ sdst_t, const int* __restrict__ offs,
    const int* __restrict__ ssorted,
    unsigned short* __restrict__ hch, unsigned short* __restrict__ hcl)
{
    __shared__ int2 sSW[4][64];
    int wv = threadIdx.x >> 6, lane = threadIdx.x & 63;
    int w = blockIdx.x * 4 + wv;
    if (w >= NN * HH) return;
    int h = w / NN, n = w - h * NN;
    const char* Hsb = (const char*)(Hh_t + (size_t)h * NN * 64);
    const float* srcs = ssrc_t + (size_t)h * NN;
    int beg = offs[n], deg = offs[n + 1] - beg;
    int g = lane >> 4, q = lane & 15;
    int qoff = q * 16;
    float4 acc = make_float4(0.f, 0.f, 0.f, 0.f);
    float den = 0.f;
    float sd = (deg > 0) ? sdst_t[(size_t)h * NN + n] : 0.f;
    for (int c0 = 0; c0 < deg; c0 += 64) {
        int jj = c0 + lane;
        int s = 0;
        float wgt = 0.f;
        if (jj < deg) {
            s = ssorted[beg + jj];
            float sv = srcs[s] + sd;
            float e = (sv >= 0.f) ? sv : LRELU_ALPHA * sv;
            wgt = __expf(e);
        }
        den += wgt;
        sSW[wv][lane] = make_int2(s << 8, __float_as_int(wgt));  // s*256 = byte offset
        int clen = min(64, deg - c0);
        int nbat = (clen + 15) >> 4;          // 1..4 batches of 4 steps (16 edges)
        for (int b = 0; b < nbat; b++) {
            int base = b * AP;
            int soff[AP];
            float wb[AP];
#pragma unroll
            for (int p2 = 0; p2 < AP; p2++) {
                int2 t2 = sSW[wv][(base + p2) * 4 + g];
                soff[p2] = t2.x;
                wb[p2] = __int_as_float(t2.y);
            }
            float4 vb[AP];
#pragma unroll
            for (int p2 = 0; p2 < AP; p2++)
                vb[p2] = *(const float4*)(Hsb + soff[p2] + qoff);
#pragma unroll
            for (int p2 = 0; p2 < AP; p2++) {
                acc.x += wb[p2] * vb[p2].x;
                acc.y += wb[p2] * vb[p2].y;
                acc.z += wb[p2] * vb[p2].z;
                acc.w += wb[p2] * vb[p2].w;
            }
        }
    }
#pragma unroll
    for (int off = 32; off; off >>= 1) den += __shfl_xor(den, off, 64);
#pragma unroll
    for (int off = 16; off < 64; off <<= 1) {
        acc.x += __shfl_xor(acc.x, off, 64);
        acc.y += __shfl_xor(acc.y, off, 64);
        acc.z += __shfl_xor(acc.z, off, 64);
        acc.w += __shfl_xor(acc.w, off, 64);
    }
    if (g == 0) {
        float inv = 1.f / (den + 1e-16f);
        float r0 = acc.x * inv, r1 = acc.y * inv, r2 = acc.z * inv, r3 = acc.w * inv;
        r0 = (r0 > 0.f) ? r0 : (__expf(r0) - 1.f);
        r1 = (r1 > 0.f) ? r1 : (__expf(r1) - 1.f);
        r2 = (r2 > 0.f) ? r2 : (__expf(r2) - 1.f);
        r3 = (r3 > 0.f) ? r3 : (__expf(r3) - 1.f);
        ushort4 vh, vl;
        bsplit(r0, vh.x, vl.x);
        bsplit(r1, vh.y, vl.y);
        bsplit(r2, vh.z, vl.z);
        bsplit(r3, vh.w, vl.w);
        size_t o = (size_t)n * HK + h * 64 + q * 4;
        unsigned long long ph =
            (unsigned long long)vh.x | ((unsigned long long)vh.y << 16) |
            ((unsigned long long)vh.z << 32) | ((unsigned long long)vh.w << 48);
        unsigned long long pl =
            (unsigned long long)vl.x | ((unsigned long long)vl.y << 16) |
            ((unsigned long long)vl.z << 32) | ((unsigned long long)vl.w << 48);
        __builtin_nontemporal_store(ph, (unsigned long long*)&hch[o]);
        __builtin_nontemporal_store(pl, (unsigned long long*)&hcl[o]);
    }
}

// ---------------------------------------------------------------- final layer + softmax
__global__ __launch_bounds__(256) void agg_final_kernel(
    const float* __restrict__ h2, const float* __restrict__ s2src,
    const float* __restrict__ s2dst, const int* __restrict__ offs,
    const int* __restrict__ ssorted, float* __restrict__ out)
{
    __shared__ int2 sSW[4][64];
    int wv = threadIdx.x >> 6, lane = threadIdx.x & 63;
    int n = blockIdx.x * 4 + wv;
    if (n >= NN) return;
    int beg = offs[n], deg = offs[n + 1] - beg;
    int g = lane >> 4, q = lane & 15;
    int qoff = q * 16;
    const char* h2b = (const char*)h2;
    float4 acc = make_float4(0.f, 0.f, 0.f, 0.f);
    float den = 0.f;
    float sd = (deg > 0) ? s2dst[n] : 0.f;
    for (int c0 = 0; c0 < deg; c0 += 64) {
        int jj = c0 + lane;
        int s = 0;
        float wgt = 0.f;
        if (jj < deg) {
            s = ssorted[beg + jj];
            float sv = s2src[s] + sd;
            float e = (sv >= 0.f) ? sv : LRELU_ALPHA * sv;
            wgt = __expf(e);
        }
        den += wgt;
        sSW[wv][lane] = make_int2(s << 8, __float_as_int(wgt));
        int clen = min(64, deg - c0);
        int nbat = (clen + 15) >> 4;
        for (int b = 0; b < nbat; b++) {
            int base = b * AP;
            int soff[AP];
            float wb[AP];
#pragma unroll
            for (int p2 = 0; p2 < AP; p2++) {
                int2 t2 = sSW[wv][(base + p2) * 4 + g];
                soff[p2] = t2.x;
                wb[p2] = __int_as_float(t2.y);
            }
            float4 vb[AP];
#pragma unroll
            for (int p2 = 0; p2 < AP; p2++)
                vb[p2] = *(const float4*)(h2b + soff[p2] + qoff);
#pragma unroll
            for (int p2 = 0; p2 < AP; p2++) {
                acc.x += wb[p2] * vb[p2].x;
                acc.y += wb[p2] * vb[p2].y;
                acc.z += wb[p2] * vb[p2].z;
                acc.w += wb[p2] * vb[p2].w;
            }
        }
    }
#pragma unroll
    for (int off = 32; off; off >>= 1) den += __shfl_xor(den, off, 64);
#pragma unroll
    for (int off = 16; off < 64; off <<= 1) {
        acc.x += __shfl_xor(acc.x, off, 64);
        acc.y += __shfl_xor(acc.y, off, 64);
        acc.z += __shfl_xor(acc.z, off, 64);
        acc.w += __shfl_xor(acc.w, off, 64);
    }
    float inv = 1.f / (den + 1e-16f);
    float r0 = acc.x * inv, r1 = acc.y * inv, r2 = acc.z * inv, r3 = acc.w * inv;
    r0 = (r0 > 0.f) ? r0 : (__expf(r0) - 1.f);
    r1 = (r1 > 0.f) ? r1 : (__expf(r1) - 1.f);
    r2 = (r2 > 0.f) ? r2 : (__expf(r2) - 1.f);
    r3 = (r3 > 0.f) ? r3 : (__expf(r3) - 1.f);
    float mm = fmaxf(fmaxf(r0, r1), fmaxf(r2, r3));
#pragma unroll
    for (int off = 1; off < 16; off <<= 1) mm = fmaxf(mm, __shfl_xor(mm, off, 64));
    float p0 = __expf(r0 - mm), p1 = __expf(r1 - mm);
    float p2 = __expf(r2 - mm), p3 = __expf(r3 - mm);
    float sum = p0 + p1 + p2 + p3;
#pragma unroll
    for (int off = 1; off < 16; off <<= 1) sum += __shfl_xor(sum, off, 64);
    float is = 1.f / sum;
    if (g == 0) {
        float4 res = make_float4(p0 * is, p1 * is, p2 * is, p3 * is);
        *(float4*)&out[(size_t)n * OO + q * 4] = res;
    }
}

// ---------------------------------------------------------------- launch
extern "C" void kernel_launch(void* const* d_in, const int* in_sizes, int n_in,
                              void* d_out, int out_size, void* d_ws, size_t ws_size,
                              hipStream_t stream) {
    const float* x       = (const float*)d_in[0];
    const int*   edges   = (const int*)d_in[1];
    const float* layer_W = (const float*)d_in[2];
    const float* layer_b = (const float*)d_in[3];
    const float* heads_W = (const float*)d_in[4];
    const float* heads_a = (const float*)d_in[5];
    const float* end_W   = (const float*)d_in[6];
    const float* end_a   = (const float*)d_in[7];
    float* out = (float*)d_out;

    const int* src = edges;
    const int* dst = edges + EE;

    char* ws = (char*)d_ws;
    size_t wsp = 0;
    auto alloc = [&](size_t bytes) -> void* {
        void* r = ws + wsp;
        wsp += (bytes + 255) & ~(size_t)255;
        return r;
    };
    // budget: ~230 MB total (round-4/6/8 footprint, known to fit)
    float* Hh_t  = (float*)alloc((size_t)NN * HK * 4);                  // 102.4 MB
    unsigned short* hch = (unsigned short*)alloc((size_t)NN * HK * 2);  // 51.2 MB
    unsigned short* hcl = (unsigned short*)alloc((size_t)NN * HK * 2);  // 51.2 MB
    float* h2    = (float*)alloc((size_t)NN * OO * 4);                  // 12.8 MB
    float* Bp    = (float*)alloc((size_t)DD * HK * 4);
    float* Wc    = (float*)alloc((size_t)DD * HK * 4);
    float* bc    = (float*)alloc((size_t)HK * 4);
    unsigned short* WexthT = (unsigned short*)alloc((size_t)NX * DD * 2);
    unsigned short* WextlT = (unsigned short*)alloc((size_t)NX * DD * 2);
    unsigned short* eexthT = (unsigned short*)alloc((size_t)N3 * HK * 2);
    unsigned short* eextlT = (unsigned short*)alloc((size_t)N3 * HK * 2);
    float* bias_ext = (float*)alloc((size_t)NX * 4);
    float* ssrc_t = (float*)alloc((size_t)HH * NN * 4);
    float* sdst_t = (float*)alloc((size_t)HH * NN * 4);
    float* s2src = (float*)alloc((size_t)NN * 4);
    float* s2dst = (float*)alloc((size_t)NN * 4);
    int* deg     = (int*)alloc((size_t)NN * 4);
    int* offs    = (int*)alloc((size_t)(NN + 1) * 4);
    int* cursor  = (int*)alloc((size_t)NN * 4);
    int* part    = (int*)alloc((size_t)NN * 4);
    int* bsum    = (int*)alloc((size_t)256 * 4);
    int* ssorted = (int*)alloc((size_t)EE * 4);

    // xh/xl alias hch/hcl: x-splits dead before agg_heads writes hch/hcl
    unsigned short* xh = hch;   // needs NN*DD*2 = 25.6 MB < 51.2 MB
    unsigned short* xl = hcl;

    const int NB = (NN + 255) / 256;   // 196 scan blocks

    (void)hipMemsetAsync(deg, 0, (size_t)NN * 4, stream);

    // weight prep
    pack_heads_kernel<<<(HH * DD * KK + 255) / 256, 256, 0, stream>>>(heads_W, Bp);
    bias_pack_kernel<<<2, 256, 0, stream>>>(layer_b, Bp, bc);
    sgemm128_kernel<<<dim3(HK / GN, DD / GM), 256, 0, stream>>>(
        layer_W, Bp, nullptr, Wc, DD, HK, DD);
    build_wext_kernel<<<(NX * DD + 255) / 256, 256, 0, stream>>>(Wc, heads_a, WexthT, WextlT);
    bias_ext_kernel<<<(NX + 255) / 256, 256, 0, stream>>>(bc, heads_a, bias_ext);
    build_eext_kernel<<<(N3 * HK + 255) / 256, 256, 0, stream>>>(end_W, end_a, eexthT, eextlT);
    split_x_kernel<<<(NN * 64 + 255) / 256, 256, 0, stream>>>(x, xh, xl);

    // GEMM1: Hh_t (head-major) + ssrc_t/sdst_t fused score columns
    mfma_gemm1_kernel<<<dim3(NX / 128, (NN + 127) / 128), 256, 0, stream>>>(
        xh, xl, WexthT, WextlT, bias_ext, Hh_t, ssrc_t, sdst_t);

    // CSR build
    hist_kernel<<<(EE + 255) / 256, 256, 0, stream>>>(dst, deg);
    scan1_kernel<<<NB, 256, 0, stream>>>(deg, part, bsum);
    scan2_kernel<<<1, 256, 0, stream>>>(bsum, NB);
    scan3_kernel<<<NB, 256, 0, stream>>>(deg, part, bsum, offs, cursor);
    scatter_kernel<<<(EE + 255) / 256, 256, 0, stream>>>(src, dst, cursor, ssorted);

    // per-head attention aggregation -> split-bf16 hcat (overwrites xh/xl region)
    agg_heads_kernel<<<(NN * HH + 3) / 4, 256, 0, stream>>>(
        Hh_t, ssrc_t, sdst_t, offs, ssorted, hch, hcl);

    // GEMM3: h2 + s2src/s2dst fused score columns
    mfma_gemm3_kernel<<<(NN + 63) / 64, 256, 0, stream>>>(
        hch, hcl, eexthT, eextlT, h2, s2src, s2dst);

    // final aggregation + elu + row softmax
    agg_final_kernel<<<(NN + 3) / 4, 256, 0, stream>>>(h2, s2src, s2dst, offs, ssorted, out);
}

// Round 11
// 902.615 us; speedup vs baseline: 1.0609x; 1.0454x over previous
//
#include <hip/hip_runtime.h>
#include <math.h>

#define NN 50000
#define DD 256
#define KK 64
#define HH 8
#define OO 64
#define EE 1600000
#define LRELU_ALPHA 0.2f
#define HK 512   // H*K
#define NX 640   // padded GEMM1 output cols (512 + 16 scores + pad)
#define N3 80    // padded GEMM3 output cols (64 + 2 scores + pad)

typedef __attribute__((ext_vector_type(8))) short short8;
typedef __attribute__((ext_vector_type(4))) float floatx4;

// split f into bf16 hi + bf16 lo (truncation; residual ~2^-16 relative)
__device__ inline void bsplit(float f, unsigned short& h, unsigned short& l) {
    unsigned u = __float_as_uint(f);
    h = (unsigned short)(u >> 16);
    float fh = __uint_as_float(u & 0xffff0000u);
    l = (unsigned short)(__float_as_uint(f - fh) >> 16);
}

// ---------------------------------------------------------------- small prep kernels
__global__ void pack_heads_kernel(const float* __restrict__ hw, float* __restrict__ Bp) {
    int t = blockIdx.x * 256 + threadIdx.x;
    if (t >= HH * DD * KK) return;
    int h = t >> 14;
    int r = t & 16383;
    int d = r >> 6;
    int k = r & 63;
    Bp[d * HK + h * KK + k] = hw[t];
}

__global__ void bias_pack_kernel(const float* __restrict__ b, const float* __restrict__ Bp,
                                 float* __restrict__ bc) {
    int c = blockIdx.x * 256 + threadIdx.x;
    if (c >= HK) return;
    float s = 0.f;
    for (int d = 0; d < DD; d++) s += b[d] * Bp[d * HK + c];
    bc[c] = s;
}

__global__ void build_wext_kernel(const float* __restrict__ Wc, const float* __restrict__ heads_a,
                                  unsigned short* __restrict__ Th, unsigned short* __restrict__ Tl) {
    int t = blockIdx.x * 256 + threadIdx.x;   // t over NX*DD
    int col = t >> 8, d = t & 255;
    if (col >= NX) return;
    float v = 0.f;
    if (col < HK) {
        v = Wc[d * HK + col];
    } else if (col < HK + 8) {
        int h = col - HK;
        for (int k = 0; k < 64; k++) v += Wc[d * HK + h * 64 + k] * heads_a[h * 128 + k];
    } else if (col < HK + 16) {
        int h = col - HK - 8;
        for (int k = 0; k < 64; k++) v += Wc[d * HK + h * 64 + k] * heads_a[h * 128 + 64 + k];
    }
    unsigned short hi, lo;
    bsplit(v, hi, lo);
    Th[(size_t)col * DD + d] = hi;
    Tl[(size_t)col * DD + d] = lo;
}

__global__ void bias_ext_kernel(const float* __restrict__ bc, const float* __restrict__ heads_a,
                                float* __restrict__ be) {
    int c = blockIdx.x * 256 + threadIdx.x;
    if (c >= NX) return;
    float v = 0.f;
    if (c < HK) v = bc[c];
    else if (c < HK + 8) {
        int h = c - HK;
        for (int k = 0; k < 64; k++) v += bc[h * 64 + k] * heads_a[h * 128 + k];
    } else if (c < HK + 16) {
        int h = c - HK - 8;
        for (int k = 0; k < 64; k++) v += bc[h * 64 + k] * heads_a[h * 128 + 64 + k];
    }
    be[c] = v;
}

__global__ void build_eext_kernel(const float* __restrict__ eW, const float* __restrict__ ea,
                                  unsigned short* __restrict__ Th, unsigned short* __restrict__ Tl) {
    int t = blockIdx.x * 256 + threadIdx.x;   // t over N3*HK
    int col = t >> 9, k = t & 511;
    if (col >= N3) return;
    float v = 0.f;
    if (col < OO) v = eW[(size_t)k * OO + col];
    else if (col == OO) { for (int j = 0; j < OO; j++) v += eW[(size_t)k * OO + j] * ea[j]; }
    else if (col == OO + 1) { for (int j = 0; j < OO; j++) v += eW[(size_t)k * OO + j] * ea[64 + j]; }
    unsigned short hi, lo;
    bsplit(v, hi, lo);
    Th[(size_t)col * HK + k] = hi;
    Tl[(size_t)col * HK + k] = lo;
}

__global__ void split_x_kernel(const float* __restrict__ x, unsigned short* __restrict__ xh,
                               unsigned short* __restrict__ xl) {
    int t = blockIdx.x * 256 + threadIdx.x;   // t over NN*64 float4s
    if (t >= NN * 64) return;
    float4 v = ((const float4*)x)[t];
    ushort4 vh, vl;
    bsplit(v.x, vh.x, vl.x);
    bsplit(v.y, vh.y, vl.y);
    bsplit(v.z, vh.z, vl.z);
    bsplit(v.w, vh.w, vl.w);
    ((ushort4*)xh)[t] = vh;
    ((ushort4*)xl)[t] = vl;
}

// ---------------------------------------------------------------- fp32 SGEMM (tiny Wc only)
#define GM 128
#define GN 128
#define GKT 16
__global__ __launch_bounds__(256) void sgemm128_kernel(
    const float* __restrict__ A, const float* __restrict__ B,
    const float* __restrict__ bias, float* __restrict__ C,
    int M, int N, int K)
{
    __shared__ float As[GKT][GM + 4];
    __shared__ float Bs[GKT][GN + 4];
    int tid = threadIdx.x;
    int row0 = blockIdx.y * GM, col0 = blockIdx.x * GN;
    int tx = tid & 15, ty = tid >> 4;
    int ar = tid >> 1;
    int ac0 = (tid & 1) * 8;
    float acc[8][8] = {};
    for (int k0 = 0; k0 < K; k0 += GKT) {
#pragma unroll
        for (int i = 0; i < 2; i++) {
            int gr = row0 + ar;
            int gc = k0 + ac0 + i * 4;
            float4 v = make_float4(0.f, 0.f, 0.f, 0.f);
            if (gr < M) v = *(const float4*)&A[(size_t)gr * K + gc];
            As[ac0 + i * 4 + 0][ar] = v.x;
            As[ac0 + i * 4 + 1][ar] = v.y;
            As[ac0 + i * 4 + 2][ar] = v.z;
            As[ac0 + i * 4 + 3][ar] = v.w;
        }
#pragma unroll
        for (int i = 0; i < 2; i++) {
            int idx = tid + i * 256;
            int br = idx >> 5;
            int bc = (idx & 31) * 4;
            float4 v = make_float4(0.f, 0.f, 0.f, 0.f);
            int gc = col0 + bc;
            if (gc < N) v = *(const float4*)&B[(size_t)(k0 + br) * N + gc];
            *(float4*)&Bs[br][bc] = v;
        }
        __syncthreads();
#pragma unroll
        for (int k = 0; k < GKT; k++) {
            float4 a0 = *(const float4*)&As[k][ty * 4];
            float4 a1 = *(const float4*)&As[k][64 + ty * 4];
            float4 b0 = *(const float4*)&Bs[k][tx * 4];
            float4 b1 = *(const float4*)&Bs[k][64 + tx * 4];
            float av[8] = {a0.x, a0.y, a0.z, a0.w, a1.x, a1.y, a1.z, a1.w};
            float bv[8] = {b0.x, b0.y, b0.z, b0.w, b1.x, b1.y, b1.z, b1.w};
#pragma unroll
            for (int i = 0; i < 8; i++)
#pragma unroll
                for (int j = 0; j < 8; j++) acc[i][j] += av[i] * bv[j];
        }
        __syncthreads();
    }
#pragma unroll
    for (int i = 0; i < 8; i++) {
        int gr = row0 + (i < 4 ? ty * 4 + i : 64 + ty * 4 + i - 4);
        if (gr >= M) continue;
#pragma unroll
        for (int j = 0; j < 8; j++) {
            int gc = col0 + (j < 4 ? tx * 4 + j : 64 + tx * 4 + j - 4);
            if (gc >= N) continue;
            float v = acc[i][j];
            if (bias) v += bias[gc];
            C[(size_t)gr * N + gc] = v;
        }
    }
}

// ---------------------------------------------------------------- GEMM1: split-bf16 MFMA
// Software-pipelined: prefetch next K-tile into registers during MFMA.
// OOB A-rows load dummy row 0 (outputs masked in epilogue).
#define LDA 40  // LDS stride in shorts
__global__ __launch_bounds__(256) void mfma_gemm1_kernel(
    const unsigned short* __restrict__ xh, const unsigned short* __restrict__ xl,
    const unsigned short* __restrict__ BhT, const unsigned short* __restrict__ BlT,
    const float* __restrict__ bias_ext,
    float* __restrict__ Hh_t, float* __restrict__ ssrc_t, float* __restrict__ sdst_t)
{
    __shared__ unsigned short AhL[128 * LDA];
    __shared__ unsigned short AlL[128 * LDA];
    __shared__ unsigned short BhL[128 * LDA];
    __shared__ unsigned short BlL[128 * LDA];
    int tid = threadIdx.x, widx = tid >> 6, lane = tid & 63;
    int row0 = blockIdx.y * 128, col0 = blockIdx.x * 128;
    int wrow = (widx >> 1) * 64, wcol = (widx & 1) * 64;
    int lrow = lane & 15, lq = lane >> 4;
    int sr = tid >> 1;            // 0..127
    int sc = (tid & 1) * 16;      // 0 or 16 (shorts)
    int gr = row0 + sr;
    size_t abase = (gr < NN) ? (size_t)gr * DD : 0;   // dummy row 0 if OOB (masked later)
    size_t bbase = (size_t)(col0 + sr) * DD;
    floatx4 acc[4][4] = {};
    uint4 pah0, pah1, pal0, pal1, pbh0, pbh1, pbl0, pbl1;
    {
        size_t ab = abase + sc, bb = bbase + sc;
        pah0 = *(const uint4*)&xh[ab];   pah1 = *(const uint4*)&xh[ab + 8];
        pal0 = *(const uint4*)&xl[ab];   pal1 = *(const uint4*)&xl[ab + 8];
        pbh0 = *(const uint4*)&BhT[bb];  pbh1 = *(const uint4*)&BhT[bb + 8];
        pbl0 = *(const uint4*)&BlT[bb];  pbl1 = *(const uint4*)&BlT[bb + 8];
    }
    for (int k0 = 0; k0 < DD; k0 += 32) {
        *(uint4*)&AhL[sr * LDA + sc]     = pah0;
        *(uint4*)&AhL[sr * LDA + sc + 8] = pah1;
        *(uint4*)&AlL[sr * LDA + sc]     = pal0;
        *(uint4*)&AlL[sr * LDA + sc + 8] = pal1;
        *(uint4*)&BhL[sr * LDA + sc]     = pbh0;
        *(uint4*)&BhL[sr * LDA + sc + 8] = pbh1;
        *(uint4*)&BlL[sr * LDA + sc]     = pbl0;
        *(uint4*)&BlL[sr * LDA + sc + 8] = pbl1;
        __syncthreads();
        if (k0 + 32 < DD) {
            size_t ab = abase + k0 + 32 + sc, bb = bbase + k0 + 32 + sc;
            pah0 = *(const uint4*)&xh[ab];   pah1 = *(const uint4*)&xh[ab + 8];
            pal0 = *(const uint4*)&xl[ab];   pal1 = *(const uint4*)&xl[ab + 8];
            pbh0 = *(const uint4*)&BhT[bb];  pbh1 = *(const uint4*)&BhT[bb + 8];
            pbl0 = *(const uint4*)&BlT[bb];  pbl1 = *(const uint4*)&BlT[bb + 8];
        }
        short8 ah[4], al[4], bh[4], bl[4];
#pragma unroll
        for (int mi = 0; mi < 4; mi++) {
            int r = wrow + mi * 16 + lrow;
            ah[mi] = *(const short8*)&AhL[r * LDA + lq * 8];
            al[mi] = *(const short8*)&AlL[r * LDA + lq * 8];
        }
#pragma unroll
        for (int ni = 0; ni < 4; ni++) {
            int c = wcol + ni * 16 + lrow;
            bh[ni] = *(const short8*)&BhL[c * LDA + lq * 8];
            bl[ni] = *(const short8*)&BlL[c * LDA + lq * 8];
        }
#pragma unroll
        for (int mi = 0; mi < 4; mi++)
#pragma unroll
            for (int ni = 0; ni < 4; ni++) {
                acc[mi][ni] = __builtin_amdgcn_mfma_f32_16x16x32_bf16(al[mi], bh[ni], acc[mi][ni], 0, 0, 0);
                acc[mi][ni] = __builtin_amdgcn_mfma_f32_16x16x32_bf16(ah[mi], bl[ni], acc[mi][ni], 0, 0, 0);
                acc[mi][ni] = __builtin_amdgcn_mfma_f32_16x16x32_bf16(ah[mi], bh[ni], acc[mi][ni], 0, 0, 0);
            }
        __syncthreads();
    }
#pragma unroll
    for (int mi = 0; mi < 4; mi++)
#pragma unroll
        for (int ni = 0; ni < 4; ni++)
#pragma unroll
            for (int r = 0; r < 4; r++) {
                int grow = row0 + wrow + mi * 16 + lq * 4 + r;
                int gcol = col0 + wcol + ni * 16 + lrow;
                if (grow < NN && gcol < HK + 16) {
                    float v = acc[mi][ni][r] + bias_ext[gcol];
                    if (gcol < HK)
                        Hh_t[((size_t)(gcol >> 6) * NN + grow) * 64 + (gcol & 63)] = v;
                    else if (gcol < HK + 8)
                        ssrc_t[(size_t)(gcol - HK) * NN + grow] = v;
                    else
                        sdst_t[(size_t)(gcol - HK - 8) * NN + grow] = v;
                }
            }
}

// ---------------------------------------------------------------- GEMM3: split-bf16 MFMA
// Software-pipelined like GEMM1. 64-row blocks, 4 waves x 16 rows, K=512.
__global__ __launch_bounds__(256) void mfma_gemm3_kernel(
    const unsigned short* __restrict__ hch, const unsigned short* __restrict__ hcl,
    const unsigned short* __restrict__ BhT, const unsigned short* __restrict__ BlT,
    float* __restrict__ h2, float* __restrict__ s2src, float* __restrict__ s2dst)
{
    __shared__ unsigned short AhL[64 * LDA];
    __shared__ unsigned short AlL[64 * LDA];
    __shared__ unsigned short BhL[N3 * LDA];
    __shared__ unsigned short BlL[N3 * LDA];
    int tid = threadIdx.x, widx = tid >> 6, lane = tid & 63;
    int row0 = blockIdx.x * 64;
    int wrow = widx * 16;
    int lrow = lane & 15, lq = lane >> 4;
    int sr = tid >> 2;            // 0..63
    int sc = (tid & 3) * 8;       // 0,8,16,24
    int gr = row0 + sr;
    size_t abase = (gr < NN) ? (size_t)gr * HK : 0;
    int bidx0 = tid;              // always < 320
    int br0 = bidx0 >> 2, bc0 = (bidx0 & 3) * 8;
    int bidx1 = tid + 256;
    bool b1ok = (bidx1 < N3 * 4);
    int br1 = bidx1 >> 2, bc1 = (bidx1 & 3) * 8;
    floatx4 acc[5] = {};
    uint4 pa0, pa1, pb0h, pb0l, pb1h, pb1l;
    {
        pa0 = *(const uint4*)&hch[abase + sc];
        pa1 = *(const uint4*)&hcl[abase + sc];
        pb0h = *(const uint4*)&BhT[(size_t)br0 * HK + bc0];
        pb0l = *(const uint4*)&BlT[(size_t)br0 * HK + bc0];
        if (b1ok) {
            pb1h = *(const uint4*)&BhT[(size_t)br1 * HK + bc1];
            pb1l = *(const uint4*)&BlT[(size_t)br1 * HK + bc1];
        }
    }
    for (int k0 = 0; k0 < HK; k0 += 32) {
        *(uint4*)&AhL[sr * LDA + sc] = pa0;
        *(uint4*)&AlL[sr * LDA + sc] = pa1;
        *(uint4*)&BhL[br0 * LDA + bc0] = pb0h;
        *(uint4*)&BlL[br0 * LDA + bc0] = pb0l;
        if (b1ok) {
            *(uint4*)&BhL[br1 * LDA + bc1] = pb1h;
            *(uint4*)&BlL[br1 * LDA + bc1] = pb1l;
        }
        __syncthreads();
        if (k0 + 32 < HK) {
            size_t ab = abase + k0 + 32 + sc;
            pa0 = *(const uint4*)&hch[ab];
            pa1 = *(const uint4*)&hcl[ab];
            pb0h = *(const uint4*)&BhT[(size_t)br0 * HK + k0 + 32 + bc0];
            pb0l = *(const uint4*)&BlT[(size_t)br0 * HK + k0 + 32 + bc0];
            if (b1ok) {
                pb1h = *(const uint4*)&BhT[(size_t)br1 * HK + k0 + 32 + bc1];
                pb1l = *(const uint4*)&BlT[(size_t)br1 * HK + k0 + 32 + bc1];
            }
        }
        short8 ah, al, bh[5], bl[5];
        int r = wrow + lrow;
        ah = *(const short8*)&AhL[r * LDA + lq * 8];
        al = *(const short8*)&AlL[r * LDA + lq * 8];
#pragma unroll
        for (int ni = 0; ni < 5; ni++) {
            int c = ni * 16 + lrow;
            bh[ni] = *(const short8*)&BhL[c * LDA + lq * 8];
            bl[ni] = *(const short8*)&BlL[c * LDA + lq * 8];
        }
#pragma unroll
        for (int ni = 0; ni < 5; ni++) {
            acc[ni] = __builtin_amdgcn_mfma_f32_16x16x32_bf16(al, bh[ni], acc[ni], 0, 0, 0);
            acc[ni] = __builtin_amdgcn_mfma_f32_16x16x32_bf16(ah, bl[ni], acc[ni], 0, 0, 0);
            acc[ni] = __builtin_amdgcn_mfma_f32_16x16x32_bf16(ah, bh[ni], acc[ni], 0, 0, 0);
        }
        __syncthreads();
    }
#pragma unroll
    for (int ni = 0; ni < 5; ni++)
#pragma unroll
        for (int r = 0; r < 4; r++) {
            int grow = row0 + wrow + lq * 4 + r;
            int gcol = ni * 16 + lrow;
            if (grow < NN) {
                float v = acc[ni][r];
                if (gcol < OO) h2[(size_t)grow * OO + gcol] = v;
                else if (gcol == OO) s2src[grow] = v;
                else if (gcol == OO + 1) s2dst[grow] = v;
            }
        }
}

// ---------------------------------------------------------------- CSR build
__global__ void hist_kernel(const int* __restrict__ dst, int* __restrict__ deg) {
    int t = blockIdx.x * 256 + threadIdx.x;
    if (t < EE) atomicAdd(&deg[dst[t]], 1);
}

__global__ void scan1_kernel(const int* __restrict__ deg, int* __restrict__ part,
                             int* __restrict__ bsum) {
    __shared__ int ws_[4];
    int i = blockIdx.x * 256 + threadIdx.x;
    int lane = threadIdx.x & 63, wv = threadIdx.x >> 6;
    int v = (i < NN) ? deg[i] : 0;
    int x = v;
#pragma unroll
    for (int d = 1; d < 64; d <<= 1) {
        int t = __shfl_up(x, d, 64);
        if (lane >= d) x += t;
    }
    if (lane == 63) ws_[wv] = x;
    __syncthreads();
    int add = 0;
    for (int k = 0; k < wv; k++) add += ws_[k];
    x += add;
    if (i < NN) part[i] = x;
    if (threadIdx.x == 255) bsum[blockIdx.x] = x;
}

__global__ void scan2_kernel(int* __restrict__ bsum, int nb) {
    __shared__ int ws_[4];
    int tid = threadIdx.x;
    int lane = tid & 63, wv = tid >> 6;
    int v = (tid < nb) ? bsum[tid] : 0;
    int x = v;
#pragma unroll
    for (int d = 1; d < 64; d <<= 1) {
        int t = __shfl_up(x, d, 64);
        if (lane >= d) x += t;
    }
    if (lane == 63) ws_[wv] = x;
    __syncthreads();
    int add = 0;
    for (int k = 0; k < wv; k++) add += ws_[k];
    x += add;
    if (tid < nb) bsum[tid] = x;
}

__global__ void scan3_kernel(const int* __restrict__ deg, const int* __restrict__ part,
                             const int* __restrict__ bsum, int* __restrict__ offs,
                             int* __restrict__ cursor) {
    int i = blockIdx.x * 256 + threadIdx.x;
    if (i >= NN) return;
    int carry = blockIdx.x ? bsum[blockIdx.x - 1] : 0;
    int incl = part[i] + carry;
    offs[i + 1] = incl;
    cursor[i] = incl - deg[i];
    if (i == 0) offs[0] = 0;
}

__global__ void scatter_kernel(const int* __restrict__ src, const int* __restrict__ dst,
                               int* __restrict__ cursor, int* __restrict__ ssorted) {
    int t = blockIdx.x * 256 + threadIdx.x;
    if (t < EE) {
        int d = dst[t];
        int pos = atomicAdd(&cursor[d], 1);
        ssorted[pos] = src[t];
    }
}

// ---------------------------------------------------------------- head aggregation
// EXACT r8 form (best measured: 341 us, VGPR=36, occupancy 73%). One wave per
// (node, head), head-major grid. No max-subtraction (|e| < ~6, exp fp32-safe,
// softmax ratio identical). (s,w) -> wave LDS -> AP=8 batches with the st<nst
// guard (keeps compiler liveness low; branch-free variants hit VGPR=60/occ 42%).
#define AP 8
__global__ __launch_bounds__(256) void agg_heads_kernel(
    const float* __restrict__ Hh_t, const float* __restrict__ ssrc_t,
    const float* __restrict__ sdst_t, const int* __restrict__ offs,
    const int* __restrict__ ssorted,
    unsigned short* __restrict__ hch, unsigned short* __restrict__ hcl)
{
    __shared__ int2 sSW[4][64];
    int wv = threadIdx.x >> 6, lane = threadIdx.x & 63;
    int w = blockIdx.x * 4 + wv;
    if (w >= NN * HH) return;
    int h = w / NN, n = w - h * NN;
    const float* Hs = Hh_t + (size_t)h * NN * 64;
    const float* srcs = ssrc_t + (size_t)h * NN;
    int beg = offs[n], deg = offs[n + 1] - beg;
    int g = lane >> 4, q = lane & 15;
    float4 acc = make_float4(0.f, 0.f, 0.f, 0.f);
    float den = 0.f;
    float sd = (deg > 0) ? sdst_t[(size_t)h * NN + n] : 0.f;
    for (int c0 = 0; c0 < deg; c0 += 64) {
        int jj = c0 + lane;
        int s = 0;
        float wgt = 0.f;
        if (jj < deg) {
            s = ssorted[beg + jj];
            float sv = srcs[s] + sd;
            float e = (sv >= 0.f) ? sv : LRELU_ALPHA * sv;
            wgt = __expf(e);
        }
        den += wgt;
        sSW[wv][lane] = make_int2(s, __float_as_int(wgt));
        int clen = min(64, deg - c0);
        int nst = (clen + 3) >> 2;
        for (int base = 0; base < nst; base += AP) {
            float4 vb[AP];
            float wb[AP];
#pragma unroll
            for (int p2 = 0; p2 < AP; p2++) {
                int st = base + p2;
                int sj = 0;
                float ww = 0.f;
                if (st < nst) {
                    int2 t2 = sSW[wv][st * 4 + g];
                    sj = t2.x;
                    ww = __int_as_float(t2.y);
                }
                wb[p2] = ww;
                vb[p2] = *(const float4*)&Hs[(size_t)sj * 64 + q * 4];
            }
#pragma unroll
            for (int p2 = 0; p2 < AP; p2++) {
                acc.x += wb[p2] * vb[p2].x;
                acc.y += wb[p2] * vb[p2].y;
                acc.z += wb[p2] * vb[p2].z;
                acc.w += wb[p2] * vb[p2].w;
            }
        }
    }
#pragma unroll
    for (int off = 32; off; off >>= 1) den += __shfl_xor(den, off, 64);
#pragma unroll
    for (int off = 16; off < 64; off <<= 1) {
        acc.x += __shfl_xor(acc.x, off, 64);
        acc.y += __shfl_xor(acc.y, off, 64);
        acc.z += __shfl_xor(acc.z, off, 64);
        acc.w += __shfl_xor(acc.w, off, 64);
    }
    if (g == 0) {
        float inv = 1.f / (den + 1e-16f);
        float r0 = acc.x * inv, r1 = acc.y * inv, r2 = acc.z * inv, r3 = acc.w * inv;
        r0 = (r0 > 0.f) ? r0 : (__expf(r0) - 1.f);
        r1 = (r1 > 0.f) ? r1 : (__expf(r1) - 1.f);
        r2 = (r2 > 0.f) ? r2 : (__expf(r2) - 1.f);
        r3 = (r3 > 0.f) ? r3 : (__expf(r3) - 1.f);
        ushort4 vh, vl;
        bsplit(r0, vh.x, vl.x);
        bsplit(r1, vh.y, vl.y);
        bsplit(r2, vh.z, vl.z);
        bsplit(r3, vh.w, vl.w);
        size_t o = (size_t)n * HK + h * 64 + q * 4;
        unsigned long long ph =
            (unsigned long long)vh.x | ((unsigned long long)vh.y << 16) |
            ((unsigned long long)vh.z << 32) | ((unsigned long long)vh.w << 48);
        unsigned long long pl =
            (unsigned long long)vl.x | ((unsigned long long)vl.y << 16) |
            ((unsigned long long)vl.z << 32) | ((unsigned long long)vl.w << 48);
        __builtin_nontemporal_store(ph, (unsigned long long*)&hch[o]);
        __builtin_nontemporal_store(pl, (unsigned long long*)&hcl[o]);
    }
}

// ---------------------------------------------------------------- final layer + softmax (r8 form)
__global__ __launch_bounds__(256) void agg_final_kernel(
    const float* __restrict__ h2, const float* __restrict__ s2src,
    const float* __restrict__ s2dst, const int* __restrict__ offs,
    const int* __restrict__ ssorted, float* __restrict__ out)
{
    __shared__ int2 sSW[4][64];
    int wv = threadIdx.x >> 6, lane = threadIdx.x & 63;
    int n = blockIdx.x * 4 + wv;
    if (n >= NN) return;
    int beg = offs[n], deg = offs[n + 1] - beg;
    int g = lane >> 4, q = lane & 15;
    float4 acc = make_float4(0.f, 0.f, 0.f, 0.f);
    float den = 0.f;
    float sd = (deg > 0) ? s2dst[n] : 0.f;
    for (int c0 = 0; c0 < deg; c0 += 64) {
        int jj = c0 + lane;
        int s = 0;
        float wgt = 0.f;
        if (jj < deg) {
            s = ssorted[beg + jj];
            float sv = s2src[s] + sd;
            float e = (sv >= 0.f) ? sv : LRELU_ALPHA * sv;
            wgt = __expf(e);
        }
        den += wgt;
        sSW[wv][lane] = make_int2(s, __float_as_int(wgt));
        int clen = min(64, deg - c0);
        int nst = (clen + 3) >> 2;
        for (int base = 0; base < nst; base += AP) {
            float4 vb[AP];
            float wb[AP];
#pragma unroll
            for (int p2 = 0; p2 < AP; p2++) {
                int st = base + p2;
                int sj = 0;
                float ww = 0.f;
                if (st < nst) {
                    int2 t2 = sSW[wv][st * 4 + g];
                    sj = t2.x;
                    ww = __int_as_float(t2.y);
                }
                wb[p2] = ww;
                vb[p2] = *(const float4*)&h2[(size_t)sj * OO + q * 4];
            }
#pragma unroll
            for (int p2 = 0; p2 < AP; p2++) {
                acc.x += wb[p2] * vb[p2].x;
                acc.y += wb[p2] * vb[p2].y;
                acc.z += wb[p2] * vb[p2].z;
                acc.w += wb[p2] * vb[p2].w;
            }
        }
    }
#pragma unroll
    for (int off = 32; off; off >>= 1) den += __shfl_xor(den, off, 64);
#pragma unroll
    for (int off = 16; off < 64; off <<= 1) {
        acc.x += __shfl_xor(acc.x, off, 64);
        acc.y += __shfl_xor(acc.y, off, 64);
        acc.z += __shfl_xor(acc.z, off, 64);
        acc.w += __shfl_xor(acc.w, off, 64);
    }
    float inv = 1.f / (den + 1e-16f);
    float r0 = acc.x * inv, r1 = acc.y * inv, r2 = acc.z * inv, r3 = acc.w * inv;
    r0 = (r0 > 0.f) ? r0 : (__expf(r0) - 1.f);
    r1 = (r1 > 0.f) ? r1 : (__expf(r1) - 1.f);
    r2 = (r2 > 0.f) ? r2 : (__expf(r2) - 1.f);
    r3 = (r3 > 0.f) ? r3 : (__expf(r3) - 1.f);
    float mm = fmaxf(fmaxf(r0, r1), fmaxf(r2, r3));
#pragma unroll
    for (int off = 1; off < 16; off <<= 1) mm = fmaxf(mm, __shfl_xor(mm, off, 64));
    float p0 = __expf(r0 - mm), p1 = __expf(r1 - mm);
    float p2 = __expf(r2 - mm), p3 = __expf(r3 - mm);
    float sum = p0 + p1 + p2 + p3;
#pragma unroll
    for (int off = 1; off < 16; off <<= 1) sum += __shfl_xor(sum, off, 64);
    float is = 1.f / sum;
    if (g == 0) {
        float4 res = make_float4(p0 * is, p1 * is, p2 * is, p3 * is);
        *(float4*)&out[(size_t)n * OO + q * 4] = res;
    }
}

// ---------------------------------------------------------------- launch
extern "C" void kernel_launch(void* const* d_in, const int* in_sizes, int n_in,
                              void* d_out, int out_size, void* d_ws, size_t ws_size,
                              hipStream_t stream) {
    const float* x       = (const float*)d_in[0];
    const int*   edges   = (const int*)d_in[1];
    const float* layer_W = (const float*)d_in[2];
    const float* layer_b = (const float*)d_in[3];
    const float* heads_W = (const float*)d_in[4];
    const float* heads_a = (const float*)d_in[5];
    const float* end_W   = (const float*)d_in[6];
    const float* end_a   = (const float*)d_in[7];
    float* out = (float*)d_out;

    const int* src = edges;
    const int* dst = edges + EE;

    char* ws = (char*)d_ws;
    size_t wsp = 0;
    auto alloc = [&](size_t bytes) -> void* {
        void* r = ws + wsp;
        wsp += (bytes + 255) & ~(size_t)255;
        return r;
    };
    // budget: ~230 MB total (round-4/6/8 footprint, known to fit)
    float* Hh_t  = (float*)alloc((size_t)NN * HK * 4);                  // 102.4 MB
    unsigned short* hch = (unsigned short*)alloc((size_t)NN * HK * 2);  // 51.2 MB
    unsigned short* hcl = (unsigned short*)alloc((size_t)NN * HK * 2);  // 51.2 MB
    float* h2    = (float*)alloc((size_t)NN * OO * 4);                  // 12.8 MB
    float* Bp    = (float*)alloc((size_t)DD * HK * 4);
    float* Wc    = (float*)alloc((size_t)DD * HK * 4);
    float* bc    = (float*)alloc((size_t)HK * 4);
    unsigned short* WexthT = (unsigned short*)alloc((size_t)NX * DD * 2);
    unsigned short* WextlT = (unsigned short*)alloc((size_t)NX * DD * 2);
    unsigned short* eexthT = (unsigned short*)alloc((size_t)N3 * HK * 2);
    unsigned short* eextlT = (unsigned short*)alloc((size_t)N3 * HK * 2);
    float* bias_ext = (float*)alloc((size_t)NX * 4);
    float* ssrc_t = (float*)alloc((size_t)HH * NN * 4);
    float* sdst_t = (float*)alloc((size_t)HH * NN * 4);
    float* s2src = (float*)alloc((size_t)NN * 4);
    float* s2dst = (float*)alloc((size_t)NN * 4);
    int* deg     = (int*)alloc((size_t)NN * 4);
    int* offs    = (int*)alloc((size_t)(NN + 1) * 4);
    int* cursor  = (int*)alloc((size_t)NN * 4);
    int* part    = (int*)alloc((size_t)NN * 4);
    int* bsum    = (int*)alloc((size_t)256 * 4);
    int* ssorted = (int*)alloc((size_t)EE * 4);

    // xh/xl alias hch/hcl: x-splits dead before agg_heads writes hch/hcl
    unsigned short* xh = hch;   // needs NN*DD*2 = 25.6 MB < 51.2 MB
    unsigned short* xl = hcl;

    const int NB = (NN + 255) / 256;   // 196 scan blocks

    (void)hipMemsetAsync(deg, 0, (size_t)NN * 4, stream);

    // weight prep
    pack_heads_kernel<<<(HH * DD * KK + 255) / 256, 256, 0, stream>>>(heads_W, Bp);
    bias_pack_kernel<<<2, 256, 0, stream>>>(layer_b, Bp, bc);
    sgemm128_kernel<<<dim3(HK / GN, DD / GM), 256, 0, stream>>>(
        layer_W, Bp, nullptr, Wc, DD, HK, DD);
    build_wext_kernel<<<(NX * DD + 255) / 256, 256, 0, stream>>>(Wc, heads_a, WexthT, WextlT);
    bias_ext_kernel<<<(NX + 255) / 256, 256, 0, stream>>>(bc, heads_a, bias_ext);
    build_eext_kernel<<<(N3 * HK + 255) / 256, 256, 0, stream>>>(end_W, end_a, eexthT, eextlT);
    split_x_kernel<<<(NN * 64 + 255) / 256, 256, 0, stream>>>(x, xh, xl);

    // GEMM1: Hh_t (head-major) + ssrc_t/sdst_t fused score columns
    mfma_gemm1_kernel<<<dim3(NX / 128, (NN + 127) / 128), 256, 0, stream>>>(
        xh, xl, WexthT, WextlT, bias_ext, Hh_t, ssrc_t, sdst_t);

    // CSR build
    hist_kernel<<<(EE + 255) / 256, 256, 0, stream>>>(dst, deg);
    scan1_kernel<<<NB, 256, 0, stream>>>(deg, part, bsum);
    scan2_kernel<<<1, 256, 0, stream>>>(bsum, NB);
    scan3_kernel<<<NB, 256, 0, stream>>>(deg, part, bsum, offs, cursor);
    scatter_kernel<<<(EE + 255) / 256, 256, 0, stream>>>(src, dst, cursor, ssorted);

    // per-head attention aggregation -> split-bf16 hcat (overwrites xh/xl region)
    agg_heads_kernel<<<(NN * HH + 3) / 4, 256, 0, stream>>>(
        Hh_t, ssrc_t, sdst_t, offs, ssorted, hch, hcl);

    // GEMM3: h2 + s2src/s2dst fused score columns
    mfma_gemm3_kernel<<<(NN + 63) / 64, 256, 0, stream>>>(
        hch, hcl, eexthT, eextlT, h2, s2src, s2dst);

    // final aggregation + elu + row softmax
    agg_final_kernel<<<(NN + 3) / 4, 256, 0, stream>>>(h2, s2src, s2dst, offs, ssorted, out);
}